// Round 10
// baseline (254.396 us; speedup 1.0000x reference)
//
#include <hip/hip_runtime.h>

constexpr int BATCH = 8;
constexpr int PPC   = 2048;            // points per cloud
constexpr int NPT   = BATCH * PPC;     // 16384 points
constexpr int OCH   = 64;              // out channels (= in channels)
constexpr int KNN_K = 20;
constexpr int NEDGE = NPT * KNN_K;     // 327680 edges
constexpr int REVCAP = 128;            // per-row reverse-adjacency capacity
constexpr int OVCAP  = 8192;           // overflow list capacity
constexpr int QCAP   = 48;             // per-point qualifier capacity
constexpr int ROWS   = 8;              // rows per gemm2_seg block

typedef short short8 __attribute__((ext_vector_type(8)));
typedef float float4v __attribute__((ext_vector_type(4)));

__device__ __forceinline__ int fmap(float f) {   // monotone float->signed-int map
  int i = __float_as_int(f);
  return i >= 0 ? i : (i ^ 0x7FFFFFFF);
}
__device__ __forceinline__ float funmap(int m) {
  int i = m >= 0 ? m : (m ^ 0x7FFFFFFF);
  return __int_as_float(i);
}
__device__ __forceinline__ unsigned short bfr(float f) {  // f32 -> bf16 RNE
  unsigned u = __float_as_uint(f);
  return (unsigned short)((u + 0x7FFFu + ((u >> 16) & 1u)) >> 16);
}
__device__ __forceinline__ short8 pack8(float4 a, float4 b) {
  short8 r;
  r[0] = (short)bfr(a.x); r[1] = (short)bfr(a.y);
  r[2] = (short)bfr(a.z); r[3] = (short)bfr(a.w);
  r[4] = (short)bfr(b.x); r[5] = (short)bfr(b.y);
  r[6] = (short)bfr(b.z); r[7] = (short)bfr(b.w);
  return r;
}
__device__ __forceinline__ unsigned umed3(unsigned a, unsigned b, unsigned c) {
  unsigned d;
  asm("v_med3_u32 %0, %1, %2, %3" : "=v"(d) : "v"(a), "v"(b), "v"(c));
  return d;
}

// ---------------------------------------------------------------- kNN ------
// Block = 16 points x 16 splits (256 threads).
// P1: per-lane top-3 distances (3 ops/cand); the 20th smallest of the 48
//     head values is a valid upper bound T' >= true 20th distance.
// P2: push candidates with d2u<=T' as u64 (d2,idx) into LDS (~25-30/point).
// P3: exact rank by pairwise u64 compare (== jax top_k (d2,index) order).
// rev[] stores the CENTER index (what gemm2 needs); ovf stores edge ids.
__global__ __launch_bounds__(256) void knn_kernel(const float* __restrict__ pos,
                                                  int* __restrict__ nbr,
                                                  int* __restrict__ cnt,
                                                  int* __restrict__ ovf_cnt,
                                                  int* __restrict__ ovf,
                                                  int* __restrict__ rev) {
  __shared__ float4 cps[8 * 257];                 // region r at r*257 (+pad)
  __shared__ unsigned long long qk[16][QCAP];     // per-point qualifiers
  __shared__ int qn[16];
  const int t  = threadIdx.x;
  const int pl = t >> 4;                     // point-local 0..15
  const int s  = t & 15;                     // split 0..15
  const int lane = t & 63;
  const int i  = blockIdx.x * 16 + pl;
  const int cbase = i & ~(PPC - 1);

  for (int u = t; u < PPC; u += 256) {
    int j = cbase + u;
    float ax = pos[3 * j], ay = pos[3 * j + 1], az = pos[3 * j + 2];
    cps[(u >> 8) * 257 + (u & 255)] = make_float4(ax, ay, az, ax * ax + ay * ay + az * az);
  }
  if (t < 16) qn[t] = 0;
  __syncthreads();

  const int il = i - cbase;
  const float4 me = cps[(il >> 8) * 257 + (il & 255)];
  const float px = me.x, py = me.y, pz = me.z, sqi = me.w;
  const int jbase = s * 128;
  const float4* __restrict__ cp = &cps[(s >> 1) * 257 + (s & 1) * 128];

  unsigned kd[3];
  kd[0] = kd[1] = kd[2] = 0xFFFFFFFFu;
  for (int u = 0; u < 128; ++u) {
    float4 c = cp[u];
    float d2 = sqi + c.w - 2.0f * (px * c.x + py * c.y + pz * c.z);
    d2 = d2 > 0.f ? d2 : 0.f;
    unsigned ck = __float_as_uint(d2);
    ck = (jbase + u == il) ? 0xFFFFFFFFu : ck;
    kd[2] = umed3(kd[1], kd[2], ck);
    kd[1] = umed3(kd[0], kd[1], ck);
    kd[0] = kd[0] < ck ? kd[0] : ck;
  }

  unsigned T = 0xFFFFFFFFu;
  int cum = 0;
  const int grp = lane & 48;
#pragma unroll
  for (int r = 0; r < KNN_K; ++r) {
    unsigned w = kd[0];
#pragma unroll
    for (int m = 1; m < 16; m <<= 1) {
      unsigned o = (unsigned)__shfl_xor((int)w, m, 16);
      w = o < w ? o : w;
    }
    bool pop = (kd[0] == w);
    unsigned long long bal = __ballot(pop);
    int mcount = __popc((int)((bal >> grp) & 0xFFFFull));
    if (cum < KNN_K) T = w;
    cum += mcount;
    if (pop) { kd[0] = kd[1]; kd[1] = kd[2]; kd[2] = 0xFFFFFFFFu; }
  }

  for (int u = 0; u < 128; ++u) {
    float4 c = cp[u];
    float d2 = sqi + c.w - 2.0f * (px * c.x + py * c.y + pz * c.z);
    d2 = d2 > 0.f ? d2 : 0.f;
    unsigned ck = __float_as_uint(d2);
    ck = (jbase + u == il) ? 0xFFFFFFFFu : ck;
    if (ck <= T) {
      int slot = atomicAdd(&qn[pl], 1);
      if (slot < QCAP)
        qk[pl][slot] = ((unsigned long long)ck << 32) | (unsigned)(jbase + u);
    }
  }
  __syncthreads();

  int n = qn[pl]; n = n < QCAP ? n : QCAP;
  for (int base = 0; base < n; base += 16) {
    int e = base + s;
    if (e < n) {
      unsigned long long mk = qk[pl][e];
      int rank = 0;
      for (int o = 0; o < n; ++o) rank += (qk[pl][o] < mk) ? 1 : 0;
      if (rank < KNN_K) {
        int j = cbase + (int)(mk & 0xFFFFFFFFull);
        int eid = i * KNN_K + rank;
        nbr[eid] = j;
        int slot = atomicAdd(&cnt[j], 1);
        if (slot < REVCAP) rev[j * REVCAP + slot] = i;   // center index
        else { int ov = atomicAdd(ovf_cnt, 1); if (ov < OVCAP) ovf[ov] = eid; }
      }
    }
  }
}

// ------------------------------------------------- node-level layer-1 GEMM -
__global__ __launch_bounds__(256) void node_gemm(const float* __restrict__ x,
                                                 const float* __restrict__ W1,
                                                 float* __restrict__ yv,
                                                 float* __restrict__ zv) {
  __shared__ float wa[64][65];
  __shared__ float wb[64][65];
  __shared__ float xs[4][64];
  const int t = threadIdx.x;
  for (int m = t; m < 8192; m += 256) {
    int o = m >> 7, c2 = m & 127;
    float w = W1[m];
    if (c2 < 64) wa[c2][o] = w; else wb[c2 - 64][o] = w;
  }
  const int nl = t >> 6, o = t & 63;
  xs[nl][o] = x[(size_t)(blockIdx.x * 4 + nl) * 64 + o];
  __syncthreads();
  float accA = 0.f, accB = 0.f;
#pragma unroll 8
  for (int c = 0; c < 64; ++c) {
    float xv = xs[nl][c];
    accA = fmaf(xv, wa[c][o], accA);
    accB = fmaf(xv, wb[c][o], accB);
  }
  size_t n = (size_t)blockIdx.x * 4 + nl;
  yv[n * 64 + o] = accA - accB;
  zv[n * 64 + o] = accB;
}

// ---------------------------- BN1 stats: center-grouped (z once, 20 y rows) -
__global__ __launch_bounds__(256) void bn1_stats(const int* __restrict__ nbr,
                                                 const float4* __restrict__ yv4,
                                                 const float4* __restrict__ zv4,
                                                 const float* __restrict__ b1,
                                                 float* __restrict__ stats) {
  const int t  = threadIdx.x;
  const int c4 = t & 15;
  const int lane = t & 63;
  const int i  = blockIdx.x * 16 + (t >> 4);
  const float4 bo = reinterpret_cast<const float4*>(b1)[c4];
  float4 z = zv4[(size_t)i * 16 + c4];
  float4 zb = make_float4(z.x + bo.x, z.y + bo.y, z.z + bo.z, z.w + bo.w);
  int jA = nbr[i * KNN_K + c4];
  int jB = nbr[i * KNN_K + 16 + (c4 & 3)];
  float4 s1 = make_float4(0, 0, 0, 0), s2 = make_float4(0, 0, 0, 0);
#pragma unroll
  for (int q = 0; q < 16; ++q) {
    int j = __shfl(jA, (lane & 48) + q);
    float4 y = yv4[(size_t)j * 16 + c4];
    float sx = y.x + zb.x, sy = y.y + zb.y, sz = y.z + zb.z, sw = y.w + zb.w;
    s1.x += sx; s1.y += sy; s1.z += sz; s1.w += sw;
    s2.x += sx * sx; s2.y += sy * sy; s2.z += sz * sz; s2.w += sw * sw;
  }
#pragma unroll
  for (int q = 0; q < 4; ++q) {
    int j = __shfl(jB, (lane & 48) + q);
    float4 y = yv4[(size_t)j * 16 + c4];
    float sx = y.x + zb.x, sy = y.y + zb.y, sz = y.z + zb.z, sw = y.w + zb.w;
    s1.x += sx; s1.y += sy; s1.z += sz; s1.w += sw;
    s2.x += sx * sx; s2.y += sy * sy; s2.z += sz * sz; s2.w += sw * sw;
  }
  s1.x += __shfl_xor(s1.x, 16); s1.y += __shfl_xor(s1.y, 16);
  s1.z += __shfl_xor(s1.z, 16); s1.w += __shfl_xor(s1.w, 16);
  s2.x += __shfl_xor(s2.x, 16); s2.y += __shfl_xor(s2.y, 16);
  s2.z += __shfl_xor(s2.z, 16); s2.w += __shfl_xor(s2.w, 16);
  s1.x += __shfl_xor(s1.x, 32); s1.y += __shfl_xor(s1.y, 32);
  s1.z += __shfl_xor(s1.z, 32); s1.w += __shfl_xor(s1.w, 32);
  s2.x += __shfl_xor(s2.x, 32); s2.y += __shfl_xor(s2.y, 32);
  s2.z += __shfl_xor(s2.z, 32); s2.w += __shfl_xor(s2.w, 32);
  __shared__ float ss[2][64];
  if (t < 128) { ss[0][t & 63] = 0.f; }
  __syncthreads();
  if ((t & 48) == 0) {
    atomicAdd(&ss[0][c4 * 4 + 0], s1.x); atomicAdd(&ss[0][c4 * 4 + 1], s1.y);
    atomicAdd(&ss[0][c4 * 4 + 2], s1.z); atomicAdd(&ss[0][c4 * 4 + 3], s1.w);
    atomicAdd(&ss[1][c4 * 4 + 0], s2.x); atomicAdd(&ss[1][c4 * 4 + 1], s2.y);
    atomicAdd(&ss[1][c4 * 4 + 2], s2.z); atomicAdd(&ss[1][c4 * 4 + 3], s2.w);
  }
  __syncthreads();
  if (t < 64)       atomicAdd(&stats[t], ss[0][t]);
  else if (t < 128) atomicAdd(&stats[64 + (t - 64)], ss[1][t - 64]);
}

// ------------- row-grouped GEMM2 (bf16 MFMA) + BN2 stats + per-row max/min -
// Block owns 8 rows. Prologue: W2 B-fragments -> 32 VGPRs; block's y rows ->
// LDS; rev entries compacted into LDS packed (row<<16)|center. Tile loop has
// a single global access (scattered z gather).
__global__ __launch_bounds__(256) void gemm2_seg(
    const float4* __restrict__ yv4, const float4* __restrict__ zv4,
    const float* __restrict__ b1, const float* __restrict__ stats1,
    const float* __restrict__ g1, const float* __restrict__ beta1,
    const float* __restrict__ W2, const float* __restrict__ b2,
    const int* __restrict__ cnt, const int* __restrict__ rev,
    float* __restrict__ stats2, int* __restrict__ mmax, int* __restrict__ mmin) {
  __shared__ unsigned short h1b[64][72];   // rows 144 B, 16-aligned
  __shared__ float4 ys[ROWS][16];
  __shared__ float a1s[64], c1s[64], b1s[64];
  __shared__ int   cct[ROWS];
  __shared__ int   offs[ROWS + 1];
  __shared__ int   eic[ROWS * REVCAP];
  __shared__ int   rowid[64];
  __shared__ int   maxt[ROWS][64];
  __shared__ int   mint[ROWS][64];
  __shared__ float ss[2][64];
  const int t = threadIdx.x;
  const int r0 = blockIdx.x * ROWS;
  constexpr float invE = 1.0f / NEDGE;
  const int eg = t >> 4, cg = t & 15;            // staging ids
  const int lane = t & 63, wv = t >> 6;          // mfma ids
  const int col = lane & 15, quad = lane >> 4;

  // B fragments (bf16 W2) into registers, once
  short8 bf0[4], bf1[4];
  const float4* __restrict__ W2v = (const float4*)W2;
#pragma unroll
  for (int nt = 0; nt < 4; ++nt) {
    int row = nt * 16 + col;
    float4 wa = W2v[row * 16 + quad * 2];
    float4 wb = W2v[row * 16 + quad * 2 + 1];
    float4 wc = W2v[row * 16 + 8 + quad * 2];
    float4 wd = W2v[row * 16 + 8 + quad * 2 + 1];
    bf0[nt] = pack8(wa, wb);
    bf1[nt] = pack8(wc, wd);
  }
  if (t < 64) {
    float mu  = stats1[t] * invE;
    float var = stats1[64 + t] * invE - mu * mu;
    float a   = g1[t] * rsqrtf(var + 1e-5f);
    a1s[t] = a; c1s[t] = beta1[t] - mu * a; b1s[t] = b1[t];
  }
  if (t < ROWS) { int c = cnt[r0 + t]; cct[t] = c < REVCAP ? c : REVCAP; }
  if (t >= 64 && t < 64 + ROWS * 16) {
    int m = t - 64;
    ys[m >> 4][m & 15] = yv4[(size_t)(r0 + (m >> 4)) * 16 + (m & 15)];
  }
  for (int m = t; m < ROWS * 64; m += 256) {
    (&maxt[0][0])[m] = 0x80000000;
    (&mint[0][0])[m] = 0x7FFFFFFF;
  }
  __syncthreads();
  if (t == 0) {
    int a = 0;
    for (int r = 0; r < ROWS; ++r) { offs[r] = a; a += cct[r]; }
    offs[ROWS] = a;
  }
  __syncthreads();
  const int total = offs[ROWS];
  // compact rev entries into LDS: eic[m] = (row<<16) | center
  for (int m = t; m < total; m += 256) {
    int lo = 0, hi = ROWS;
#pragma unroll
    for (int st = 0; st < 3; ++st) {
      int mid = (lo + hi) >> 1;
      if (m >= offs[mid]) lo = mid; else hi = mid;
    }
    int ic = rev[(size_t)(r0 + lo) * REVCAP + (m - offs[lo])];
    eic[m] = (lo << 16) | ic;
  }

  float a1r[4], c1r[4], b1r[4];
#pragma unroll
  for (int q = 0; q < 4; ++q) {
    a1r[q] = a1s[cg * 4 + q]; c1r[q] = c1s[cg * 4 + q]; b1r[q] = b1s[cg * 4 + q];
  }
  float b2r[4];
#pragma unroll
  for (int nt = 0; nt < 4; ++nt) b2r[nt] = b2[nt * 16 + col];
  float s1[4] = {0, 0, 0, 0}, s2[4] = {0, 0, 0, 0};
  const int ntiles = (total + 63) >> 6;
  for (int ti = 0; ti < ntiles; ++ti) {
    __syncthreads();
#pragma unroll
    for (int k = 0; k < 4; ++k) {
      int el = k * 16 + eg;
      int m  = ti * 64 + el;
      bool valid = m < total;
      int pk = valid ? eic[m] : 0;
      int r = pk >> 16, ic = pk & 0xFFFF;
      float4 y = ys[r][cg];
      float4 z = zv4[(size_t)ic * 16 + cg];
      float h0 = fmaf(y.x + z.x + b1r[0], a1r[0], c1r[0]);
      float h1 = fmaf(y.y + z.y + b1r[1], a1r[1], c1r[1]);
      float h2 = fmaf(y.z + z.z + b1r[2], a1r[2], c1r[2]);
      float h3 = fmaf(y.w + z.w + b1r[3], a1r[3], c1r[3]);
      h0 = h0 > 0.f ? h0 : 0.f; h1 = h1 > 0.f ? h1 : 0.f;
      h2 = h2 > 0.f ? h2 : 0.f; h3 = h3 > 0.f ? h3 : 0.f;
      uint2 p;
      p.x = (unsigned)bfr(h0) | ((unsigned)bfr(h1) << 16);
      p.y = (unsigned)bfr(h2) | ((unsigned)bfr(h3) << 16);
      *reinterpret_cast<uint2*>(&h1b[el][cg * 4]) = p;
      if (cg == 0) rowid[el] = valid ? r : -1;
    }
    __syncthreads();
    float4v acc[4];
#pragma unroll
    for (int nt = 0; nt < 4; ++nt) acc[nt] = (float4v){0.f, 0.f, 0.f, 0.f};
    short8 af0 = *reinterpret_cast<const short8*>(&h1b[wv * 16 + col][quad * 8]);
    short8 af1 = *reinterpret_cast<const short8*>(&h1b[wv * 16 + col][32 + quad * 8]);
#pragma unroll
    for (int nt = 0; nt < 4; ++nt) {
      acc[nt] = __builtin_amdgcn_mfma_f32_16x16x32_bf16(af0, bf0[nt], acc[nt], 0, 0, 0);
      acc[nt] = __builtin_amdgcn_mfma_f32_16x16x32_bf16(af1, bf1[nt], acc[nt], 0, 0, 0);
    }
    const int eb = wv * 16 + quad * 4;
    int cur = -1;
    float mx[4], mn[4];
#pragma unroll
    for (int r = 0; r < 4; ++r) {
      int rw = rowid[eb + r];
      float v[4];
#pragma unroll
      for (int nt = 0; nt < 4; ++nt) v[nt] = acc[nt][r] + b2r[nt];
      if (rw >= 0) {
#pragma unroll
        for (int nt = 0; nt < 4; ++nt) { s1[nt] += v[nt]; s2[nt] += v[nt] * v[nt]; }
      }
      if (rw != cur) {
        if (cur >= 0) {
#pragma unroll
          for (int nt = 0; nt < 4; ++nt) {
            atomicMax(&maxt[cur][nt * 16 + col], fmap(mx[nt]));
            atomicMin(&mint[cur][nt * 16 + col], fmap(mn[nt]));
          }
        }
        cur = rw;
#pragma unroll
        for (int nt = 0; nt < 4; ++nt) { mx[nt] = v[nt]; mn[nt] = v[nt]; }
      } else if (rw >= 0) {
#pragma unroll
        for (int nt = 0; nt < 4; ++nt) {
          mx[nt] = v[nt] > mx[nt] ? v[nt] : mx[nt];
          mn[nt] = v[nt] < mn[nt] ? v[nt] : mn[nt];
        }
      }
    }
    if (cur >= 0) {
#pragma unroll
      for (int nt = 0; nt < 4; ++nt) {
        atomicMax(&maxt[cur][nt * 16 + col], fmap(mx[nt]));
        atomicMin(&mint[cur][nt * 16 + col], fmap(mn[nt]));
      }
    }
  }
  __syncthreads();
  for (int m = t; m < ROWS * 64; m += 256) {
    int r = m >> 6, c = m & 63;
    mmax[(size_t)(r0 + r) * 64 + c] = maxt[r][c];
    mmin[(size_t)(r0 + r) * 64 + c] = mint[r][c];
  }
  if (t < 64) { ss[0][t] = 0.f; ss[1][t] = 0.f; }
  __syncthreads();
#pragma unroll
  for (int nt = 0; nt < 4; ++nt) {
    s1[nt] += __shfl_xor(s1[nt], 16);
    s1[nt] += __shfl_xor(s1[nt], 32);
    s2[nt] += __shfl_xor(s2[nt], 16);
    s2[nt] += __shfl_xor(s2[nt], 32);
  }
  if ((t & 48) == 0) {
#pragma unroll
    for (int nt = 0; nt < 4; ++nt) {
      atomicAdd(&ss[0][nt * 16 + col], s1[nt]);
      atomicAdd(&ss[1][nt * 16 + col], s2[nt]);
    }
  }
  __syncthreads();
  if (t < 64)       atomicAdd(&stats2[t], ss[0][t]);
  else if (t < 128) atomicAdd(&stats2[t - 64 + 64], ss[1][t - 64]);
}

// ---------------- finalize: BN2 affine of per-row max/min + relu + empties -
__global__ __launch_bounds__(256) void finalize_out(
    const float* __restrict__ stats2, const float* __restrict__ g2,
    const float* __restrict__ beta2, const int* __restrict__ cnt,
    const int* __restrict__ mmax, const int* __restrict__ mmin,
    const int* __restrict__ ovf_cnt, const int* __restrict__ ovf,
    const int* __restrict__ nbr, const float* __restrict__ yv,
    const float* __restrict__ zv, const float* __restrict__ b1,
    const float* __restrict__ stats1, const float* __restrict__ g1,
    const float* __restrict__ beta1, const float* __restrict__ W2,
    const float* __restrict__ b2, float* __restrict__ outp) {
  const int idx = blockIdx.x * 256 + threadIdx.x;
  const int row = idx >> 6, ch = idx & 63;
  constexpr float invE = 1.0f / NEDGE;
  float mu  = stats2[ch] * invE;
  float var = stats2[64 + ch] * invE - mu * mu;
  float a2  = g2[ch] * rsqrtf(var + 1e-5f);
  float c2  = beta2[ch] - mu * a2;
  float h = (a2 >= 0.f) ? funmap(mmax[idx]) : funmap(mmin[idx]);
  int ov = ovf_cnt[0]; ov = ov > OVCAP ? OVCAP : ov;
  for (int u = 0; u < ov; ++u) {
    int e = ovf[u];
    if (nbr[e] == row) {
      int ic = e / KNN_K;
      float accv = 0.f;
      for (int k = 0; k < 64; ++k) {
        float mu1  = stats1[k] * invE;
        float var1 = stats1[64 + k] * invE - mu1 * mu1;
        float a1   = g1[k] * rsqrtf(var1 + 1e-5f);
        float c1   = beta1[k] - mu1 * a1;
        float sI   = yv[(size_t)row * 64 + k] + zv[(size_t)ic * 64 + k] + b1[k];
        float hh   = fmaf(sI, a1, c1);
        hh = hh > 0.f ? hh : 0.f;
        accv = fmaf(hh, W2[ch * 64 + k], accv);
      }
      float v = accv + b2[ch];
      if (a2 >= 0.f) h = v > h ? v : h; else h = v < h ? v : h;
    }
  }
  float o = (cnt[row] > 0) ? fmaf(h, a2, c2) : 0.0f;
  outp[idx] = o > 0.f ? o : 0.f;
}

// --------------------------------------------------------------- launch ----
extern "C" void kernel_launch(void* const* d_in, const int* in_sizes, int n_in,
                              void* d_out, int out_size, void* d_ws, size_t ws_size,
                              hipStream_t stream) {
  (void)in_sizes; (void)n_in; (void)out_size; (void)ws_size;
  const float* x     = (const float*)d_in[0];
  const float* pos   = (const float*)d_in[1];
  const float* W1    = (const float*)d_in[3];
  const float* b1    = (const float*)d_in[4];
  const float* g1    = (const float*)d_in[5];
  const float* beta1 = (const float*)d_in[6];
  const float* W2    = (const float*)d_in[7];
  const float* b2    = (const float*)d_in[8];
  const float* g2    = (const float*)d_in[9];
  const float* beta2 = (const float*)d_in[10];
  float* outp = (float*)d_out;

  char* w = (char*)d_ws;
  int*   nbr     = (int*)w;                            // 1,310,720 B
  float* yv      = (float*)(w + 1310720);              // 4,194,304 B
  float* zv      = (float*)(w + 5505024);              // 4,194,304 B
  float* stats   = (float*)(w + 9699328);              // 1,024 B
  int*   cnt     = (int*)(w + 9700352);                // 65,536 B
  int*   ovf_cnt = (int*)(w + 9765888);                // 64 B
  int*   ovf     = (int*)(w + 9765952);                // 32,768 B
  int*   rev     = (int*)(w + 9798720);                // 8,388,608 B -> 18,187,328
  int*   mmax    = (int*)(w + 18187328);               // 4,194,304 B
  int*   mmin    = (int*)(w + 22381632);               // 4,194,304 B -> 26,575,936

  hipMemsetAsync(stats, 0, 1024, stream);
  hipMemsetAsync(cnt, 0, 65536 + 64, stream);

  knn_kernel<<<NPT / 16, 256, 0, stream>>>(pos, nbr, cnt, ovf_cnt, ovf, rev);
  node_gemm<<<NPT / 4, 256, 0, stream>>>(x, W1, yv, zv);
  bn1_stats<<<NPT / 16, 256, 0, stream>>>(nbr, (const float4*)yv, (const float4*)zv, b1, stats);
  gemm2_seg<<<NPT / ROWS, 256, 0, stream>>>(
      (const float4*)yv, (const float4*)zv, b1, stats, g1, beta1, W2, b2,
      cnt, rev, stats + 128, mmax, mmin);
  finalize_out<<<NPT * 64 / 256, 256, 0, stream>>>(
      stats + 128, g2, beta2, cnt, mmax, mmin, ovf_cnt, ovf, nbr,
      yv, zv, b1, stats, g1, beta1, W2, b2, outp);
}

// Round 11
// 241.050 us; speedup vs baseline: 1.0554x; 1.0554x over previous
//
#include <hip/hip_runtime.h>

constexpr int BATCH = 8;
constexpr int PPC   = 2048;            // points per cloud
constexpr int NPT   = BATCH * PPC;     // 16384 points
constexpr int OCH   = 64;              // out channels (= in channels)
constexpr int KNN_K = 20;
constexpr int NEDGE = NPT * KNN_K;     // 327680 edges
constexpr int REVCAP = 128;            // per-row reverse-adjacency capacity
constexpr int OVCAP  = 8192;           // overflow list capacity
constexpr int QCAP   = 48;             // per-point qualifier capacity

typedef short short8 __attribute__((ext_vector_type(8)));
typedef float float4v __attribute__((ext_vector_type(4)));

__device__ __forceinline__ unsigned short bfr(float f) {  // f32 -> bf16 RNE
  unsigned u = __float_as_uint(f);
  return (unsigned short)((u + 0x7FFFu + ((u >> 16) & 1u)) >> 16);
}
__device__ __forceinline__ short8 pack8(float4 a, float4 b) {
  short8 r;
  r[0] = (short)bfr(a.x); r[1] = (short)bfr(a.y);
  r[2] = (short)bfr(a.z); r[3] = (short)bfr(a.w);
  r[4] = (short)bfr(b.x); r[5] = (short)bfr(b.y);
  r[6] = (short)bfr(b.z); r[7] = (short)bfr(b.w);
  return r;
}
__device__ __forceinline__ unsigned umed3(unsigned a, unsigned b, unsigned c) {
  unsigned d;
  asm("v_med3_u32 %0, %1, %2, %3" : "=v"(d) : "v"(a), "v"(b), "v"(c));
  return d;
}

// ---------------------------------------------------------------- kNN ------
// Block = 16 points x 16 splits (256 threads). Top-3-per-lane bound T',
// qualifier push, exact (d2,index) rank. rev[] stores CENTER index.
__global__ __launch_bounds__(256) void knn_kernel(const float* __restrict__ pos,
                                                  int* __restrict__ nbr,
                                                  int* __restrict__ cnt,
                                                  int* __restrict__ ovf_cnt,
                                                  int* __restrict__ ovf,
                                                  int* __restrict__ rev) {
  __shared__ float4 cps[8 * 257];                 // region r at r*257 (+pad)
  __shared__ unsigned long long qk[16][QCAP];     // per-point qualifiers
  __shared__ int qn[16];
  const int t  = threadIdx.x;
  const int pl = t >> 4;                     // point-local 0..15
  const int s  = t & 15;                     // split 0..15
  const int lane = t & 63;
  const int i  = blockIdx.x * 16 + pl;
  const int cbase = i & ~(PPC - 1);

  for (int u = t; u < PPC; u += 256) {
    int j = cbase + u;
    float ax = pos[3 * j], ay = pos[3 * j + 1], az = pos[3 * j + 2];
    cps[(u >> 8) * 257 + (u & 255)] = make_float4(ax, ay, az, ax * ax + ay * ay + az * az);
  }
  if (t < 16) qn[t] = 0;
  __syncthreads();

  const int il = i - cbase;
  const float4 me = cps[(il >> 8) * 257 + (il & 255)];
  const float px = me.x, py = me.y, pz = me.z, sqi = me.w;
  const int jbase = s * 128;
  const float4* __restrict__ cp = &cps[(s >> 1) * 257 + (s & 1) * 128];

  unsigned kd[3];
  kd[0] = kd[1] = kd[2] = 0xFFFFFFFFu;
  for (int u = 0; u < 128; ++u) {
    float4 c = cp[u];
    float d2 = sqi + c.w - 2.0f * (px * c.x + py * c.y + pz * c.z);
    d2 = d2 > 0.f ? d2 : 0.f;
    unsigned ck = __float_as_uint(d2);
    ck = (jbase + u == il) ? 0xFFFFFFFFu : ck;
    kd[2] = umed3(kd[1], kd[2], ck);
    kd[1] = umed3(kd[0], kd[1], ck);
    kd[0] = kd[0] < ck ? kd[0] : ck;
  }

  unsigned T = 0xFFFFFFFFu;
  int cum = 0;
  const int grp = lane & 48;
#pragma unroll
  for (int r = 0; r < KNN_K; ++r) {
    unsigned w = kd[0];
#pragma unroll
    for (int m = 1; m < 16; m <<= 1) {
      unsigned o = (unsigned)__shfl_xor((int)w, m, 16);
      w = o < w ? o : w;
    }
    bool pop = (kd[0] == w);
    unsigned long long bal = __ballot(pop);
    int mcount = __popc((int)((bal >> grp) & 0xFFFFull));
    if (cum < KNN_K) T = w;
    cum += mcount;
    if (pop) { kd[0] = kd[1]; kd[1] = kd[2]; kd[2] = 0xFFFFFFFFu; }
  }

  for (int u = 0; u < 128; ++u) {
    float4 c = cp[u];
    float d2 = sqi + c.w - 2.0f * (px * c.x + py * c.y + pz * c.z);
    d2 = d2 > 0.f ? d2 : 0.f;
    unsigned ck = __float_as_uint(d2);
    ck = (jbase + u == il) ? 0xFFFFFFFFu : ck;
    if (ck <= T) {
      int slot = atomicAdd(&qn[pl], 1);
      if (slot < QCAP)
        qk[pl][slot] = ((unsigned long long)ck << 32) | (unsigned)(jbase + u);
    }
  }
  __syncthreads();

  int n = qn[pl]; n = n < QCAP ? n : QCAP;
  for (int base = 0; base < n; base += 16) {
    int e = base + s;
    if (e < n) {
      unsigned long long mk = qk[pl][e];
      int rank = 0;
      for (int o = 0; o < n; ++o) rank += (qk[pl][o] < mk) ? 1 : 0;
      if (rank < KNN_K) {
        int j = cbase + (int)(mk & 0xFFFFFFFFull);
        int eid = i * KNN_K + rank;
        nbr[eid] = j;
        int slot = atomicAdd(&cnt[j], 1);
        if (slot < REVCAP) rev[j * REVCAP + slot] = i;   // center index
        else { int ov = atomicAdd(ovf_cnt, 1); if (ov < OVCAP) ovf[ov] = eid; }
      }
    }
  }
}

// ------------------------------------------------- node-level layer-1 GEMM -
__global__ __launch_bounds__(256) void node_gemm(const float* __restrict__ x,
                                                 const float* __restrict__ W1,
                                                 float* __restrict__ yv,
                                                 float* __restrict__ zv) {
  __shared__ float wa[64][65];
  __shared__ float wb[64][65];
  __shared__ float xs[4][64];
  const int t = threadIdx.x;
  for (int m = t; m < 8192; m += 256) {
    int o = m >> 7, c2 = m & 127;
    float w = W1[m];
    if (c2 < 64) wa[c2][o] = w; else wb[c2 - 64][o] = w;
  }
  const int nl = t >> 6, o = t & 63;
  xs[nl][o] = x[(size_t)(blockIdx.x * 4 + nl) * 64 + o];
  __syncthreads();
  float accA = 0.f, accB = 0.f;
#pragma unroll 8
  for (int c = 0; c < 64; ++c) {
    float xv = xs[nl][c];
    accA = fmaf(xv, wa[c][o], accA);
    accB = fmaf(xv, wb[c][o], accB);
  }
  size_t n = (size_t)blockIdx.x * 4 + nl;
  yv[n * 64 + o] = accA - accB;
  zv[n * 64 + o] = accB;
}

// ---------------------------- BN1 stats: center-grouped (z once, 20 y rows) -
__global__ __launch_bounds__(256) void bn1_stats(const int* __restrict__ nbr,
                                                 const float4* __restrict__ yv4,
                                                 const float4* __restrict__ zv4,
                                                 const float* __restrict__ b1,
                                                 float* __restrict__ stats) {
  const int t  = threadIdx.x;
  const int c4 = t & 15;
  const int lane = t & 63;
  const int i  = blockIdx.x * 16 + (t >> 4);
  const float4 bo = reinterpret_cast<const float4*>(b1)[c4];
  float4 z = zv4[(size_t)i * 16 + c4];
  float4 zb = make_float4(z.x + bo.x, z.y + bo.y, z.z + bo.z, z.w + bo.w);
  int jA = nbr[i * KNN_K + c4];
  int jB = nbr[i * KNN_K + 16 + (c4 & 3)];
  float4 s1 = make_float4(0, 0, 0, 0), s2 = make_float4(0, 0, 0, 0);
#pragma unroll
  for (int q = 0; q < 16; ++q) {
    int j = __shfl(jA, (lane & 48) + q);
    float4 y = yv4[(size_t)j * 16 + c4];
    float sx = y.x + zb.x, sy = y.y + zb.y, sz = y.z + zb.z, sw = y.w + zb.w;
    s1.x += sx; s1.y += sy; s1.z += sz; s1.w += sw;
    s2.x += sx * sx; s2.y += sy * sy; s2.z += sz * sz; s2.w += sw * sw;
  }
#pragma unroll
  for (int q = 0; q < 4; ++q) {
    int j = __shfl(jB, (lane & 48) + q);
    float4 y = yv4[(size_t)j * 16 + c4];
    float sx = y.x + zb.x, sy = y.y + zb.y, sz = y.z + zb.z, sw = y.w + zb.w;
    s1.x += sx; s1.y += sy; s1.z += sz; s1.w += sw;
    s2.x += sx * sx; s2.y += sy * sy; s2.z += sz * sz; s2.w += sw * sw;
  }
  s1.x += __shfl_xor(s1.x, 16); s1.y += __shfl_xor(s1.y, 16);
  s1.z += __shfl_xor(s1.z, 16); s1.w += __shfl_xor(s1.w, 16);
  s2.x += __shfl_xor(s2.x, 16); s2.y += __shfl_xor(s2.y, 16);
  s2.z += __shfl_xor(s2.z, 16); s2.w += __shfl_xor(s2.w, 16);
  s1.x += __shfl_xor(s1.x, 32); s1.y += __shfl_xor(s1.y, 32);
  s1.z += __shfl_xor(s1.z, 32); s1.w += __shfl_xor(s1.w, 32);
  s2.x += __shfl_xor(s2.x, 32); s2.y += __shfl_xor(s2.y, 32);
  s2.z += __shfl_xor(s2.z, 32); s2.w += __shfl_xor(s2.w, 32);
  __shared__ float ss[2][64];
  if (t < 128) { ss[0][t & 63] = 0.f; }
  __syncthreads();
  if ((t & 48) == 0) {
    atomicAdd(&ss[0][c4 * 4 + 0], s1.x); atomicAdd(&ss[0][c4 * 4 + 1], s1.y);
    atomicAdd(&ss[0][c4 * 4 + 2], s1.z); atomicAdd(&ss[0][c4 * 4 + 3], s1.w);
    atomicAdd(&ss[1][c4 * 4 + 0], s2.x); atomicAdd(&ss[1][c4 * 4 + 1], s2.y);
    atomicAdd(&ss[1][c4 * 4 + 2], s2.z); atomicAdd(&ss[1][c4 * 4 + 3], s2.w);
  }
  __syncthreads();
  if (t < 64)       atomicAdd(&stats[t], ss[0][t]);
  else if (t < 128) atomicAdd(&stats[64 + (t - 64)], ss[1][t - 64]);
}

// ----------- per-wave row-owned GEMM2 (bf16 MFMA), barrier-free hot loop ---
// One wave owns 4 output rows. rev centers live in 2 VGPRs (shfl broadcast);
// W2 B-fragments in VGPRs; h1 tile staged in a private LDS slice with
// s_waitcnt lgkmcnt(0) (same-wave ordering) instead of __syncthreads.
// Per-row max/min reduced in registers (shfl across quads), plain-stored.
__global__ __launch_bounds__(256) void gemm2_row(
    const float4* __restrict__ yv4, const float4* __restrict__ zv4,
    const float* __restrict__ b1, const float* __restrict__ stats1,
    const float* __restrict__ g1, const float* __restrict__ beta1,
    const float* __restrict__ W2, const float* __restrict__ b2,
    const int* __restrict__ cnt, const int* __restrict__ rev,
    float* __restrict__ stats2, float* __restrict__ mmax,
    float* __restrict__ mmin) {
  __shared__ unsigned short h1b[4][16][72];   // per-wave 16-edge tile
  __shared__ float ss[2][64];
  const int t = threadIdx.x, wv = t >> 6, lane = t & 63;
  const int col = lane & 15, quad = lane >> 4;
  const int wid = blockIdx.x * 4 + wv;
  constexpr float invE = 1.0f / NEDGE;

  // BN1 coefs for this lane's staging channels (col*4 .. col*4+3)
  float a1r[4], c1r[4], b1r[4];
#pragma unroll
  for (int q = 0; q < 4; ++q) {
    int ch = col * 4 + q;
    float mu  = stats1[ch] * invE;
    float var = stats1[64 + ch] * invE - mu * mu;
    float a   = g1[ch] * rsqrtf(var + 1e-5f);
    a1r[q] = a; c1r[q] = beta1[ch] - mu * a; b1r[q] = b1[ch];
  }
  // W2 B-fragments into registers
  short8 bf0[4], bf1[4];
  const float4* __restrict__ W2v = (const float4*)W2;
#pragma unroll
  for (int nt = 0; nt < 4; ++nt) {
    int row = nt * 16 + col;
    float4 wa = W2v[row * 16 + quad * 2];
    float4 wb = W2v[row * 16 + quad * 2 + 1];
    float4 wc = W2v[row * 16 + 8 + quad * 2];
    float4 wd = W2v[row * 16 + 8 + quad * 2 + 1];
    bf0[nt] = pack8(wa, wb);
    bf1[nt] = pack8(wc, wd);
  }
  float b2r[4];
#pragma unroll
  for (int nt = 0; nt < 4; ++nt) b2r[nt] = b2[nt * 16 + col];

  float s1[4] = {0, 0, 0, 0}, s2[4] = {0, 0, 0, 0};
  for (int row = wid * 4; row < wid * 4 + 4; ++row) {
    int n = cnt[row]; n = n < REVCAP ? n : REVCAP;
    int rv0 = (lane < n) ? rev[(size_t)row * REVCAP + lane] : 0;
    int rv1 = (64 + lane < n) ? rev[(size_t)row * REVCAP + 64 + lane] : 0;
    float4 y = yv4[(size_t)row * 16 + col];
    float mx[4], mn[4];
#pragma unroll
    for (int nt = 0; nt < 4; ++nt) { mx[nt] = -1e30f; mn[nt] = 1e30f; }
    const int ntile = (n + 15) >> 4;
    for (int ti = 0; ti < ntile; ++ti) {
#pragma unroll
      for (int k = 0; k < 4; ++k) {
        int el = k * 4 + quad;
        int gi = ti * 16 + el;
        int v0 = __shfl(rv0, gi & 63);
        int v1 = __shfl(rv1, gi & 63);
        int ic = (gi < 64) ? v0 : v1;
        ic = (gi < n) ? ic : 0;
        float4 z = zv4[(size_t)ic * 16 + col];
        float h0 = fmaf(y.x + z.x + b1r[0], a1r[0], c1r[0]);
        float h1 = fmaf(y.y + z.y + b1r[1], a1r[1], c1r[1]);
        float h2 = fmaf(y.z + z.z + b1r[2], a1r[2], c1r[2]);
        float h3 = fmaf(y.w + z.w + b1r[3], a1r[3], c1r[3]);
        h0 = h0 > 0.f ? h0 : 0.f; h1 = h1 > 0.f ? h1 : 0.f;
        h2 = h2 > 0.f ? h2 : 0.f; h3 = h3 > 0.f ? h3 : 0.f;
        uint2 p;
        p.x = (unsigned)bfr(h0) | ((unsigned)bfr(h1) << 16);
        p.y = (unsigned)bfr(h2) | ((unsigned)bfr(h3) << 16);
        *reinterpret_cast<uint2*>(&h1b[wv][el][col * 4]) = p;
      }
      __asm__ volatile("s_waitcnt lgkmcnt(0)" ::: "memory");
      short8 af0 = *reinterpret_cast<const short8*>(&h1b[wv][col][quad * 8]);
      short8 af1 = *reinterpret_cast<const short8*>(&h1b[wv][col][32 + quad * 8]);
      float4v acc[4];
#pragma unroll
      for (int nt = 0; nt < 4; ++nt) {
        acc[nt] = (float4v){0.f, 0.f, 0.f, 0.f};
        acc[nt] = __builtin_amdgcn_mfma_f32_16x16x32_bf16(af0, bf0[nt], acc[nt], 0, 0, 0);
        acc[nt] = __builtin_amdgcn_mfma_f32_16x16x32_bf16(af1, bf1[nt], acc[nt], 0, 0, 0);
      }
      __asm__ volatile("s_waitcnt lgkmcnt(0)" ::: "memory");  // reads done before next overwrite
#pragma unroll
      for (int r = 0; r < 4; ++r) {
        bool v = (ti * 16 + quad * 4 + r) < n;
#pragma unroll
        for (int nt = 0; nt < 4; ++nt) {
          float val = acc[nt][r] + b2r[nt];
          if (v) {
            s1[nt] += val; s2[nt] += val * val;
            mx[nt] = val > mx[nt] ? val : mx[nt];
            mn[nt] = val < mn[nt] ? val : mn[nt];
          }
        }
      }
    }
    // reduce max/min across quads (lanes sharing col)
#pragma unroll
    for (int nt = 0; nt < 4; ++nt) {
      mx[nt] = fmaxf(mx[nt], __shfl_xor(mx[nt], 16));
      mx[nt] = fmaxf(mx[nt], __shfl_xor(mx[nt], 32));
      mn[nt] = fminf(mn[nt], __shfl_xor(mn[nt], 16));
      mn[nt] = fminf(mn[nt], __shfl_xor(mn[nt], 32));
    }
    if (quad == 0) {
#pragma unroll
      for (int nt = 0; nt < 4; ++nt) {
        mmax[(size_t)row * 64 + nt * 16 + col] = mx[nt];
        mmin[(size_t)row * 64 + nt * 16 + col] = mn[nt];
      }
    }
  }
  // block-level stats reduction
  if (t < 128) ss[t >> 6][t & 63] = 0.f;
  __syncthreads();
#pragma unroll
  for (int nt = 0; nt < 4; ++nt) {
    s1[nt] += __shfl_xor(s1[nt], 16);
    s1[nt] += __shfl_xor(s1[nt], 32);
    s2[nt] += __shfl_xor(s2[nt], 16);
    s2[nt] += __shfl_xor(s2[nt], 32);
  }
  if (quad == 0) {
#pragma unroll
    for (int nt = 0; nt < 4; ++nt) {
      atomicAdd(&ss[0][nt * 16 + col], s1[nt]);
      atomicAdd(&ss[1][nt * 16 + col], s2[nt]);
    }
  }
  __syncthreads();
  if (t < 64)       atomicAdd(&stats2[t], ss[0][t]);
  else if (t < 128) atomicAdd(&stats2[64 + (t - 64)], ss[1][t - 64]);
}

// ---------------- finalize: BN2 affine of per-row max/min + relu + empties -
__global__ __launch_bounds__(256) void finalize_out(
    const float* __restrict__ stats2, const float* __restrict__ g2,
    const float* __restrict__ beta2, const int* __restrict__ cnt,
    const float* __restrict__ mmax, const float* __restrict__ mmin,
    const int* __restrict__ ovf_cnt, const int* __restrict__ ovf,
    const int* __restrict__ nbr, const float* __restrict__ yv,
    const float* __restrict__ zv, const float* __restrict__ b1,
    const float* __restrict__ stats1, const float* __restrict__ g1,
    const float* __restrict__ beta1, const float* __restrict__ W2,
    const float* __restrict__ b2, float* __restrict__ outp) {
  const int idx = blockIdx.x * 256 + threadIdx.x;
  const int row = idx >> 6, ch = idx & 63;
  constexpr float invE = 1.0f / NEDGE;
  float mu  = stats2[ch] * invE;
  float var = stats2[64 + ch] * invE - mu * mu;
  float a2  = g2[ch] * rsqrtf(var + 1e-5f);
  float c2  = beta2[ch] - mu * a2;
  float h = (a2 >= 0.f) ? mmax[idx] : mmin[idx];
  int ov = ovf_cnt[0]; ov = ov > OVCAP ? OVCAP : ov;
  for (int u = 0; u < ov; ++u) {
    int e = ovf[u];
    if (nbr[e] == row) {
      int ic = e / KNN_K;
      float accv = 0.f;
      for (int k = 0; k < 64; ++k) {
        float mu1  = stats1[k] * invE;
        float var1 = stats1[64 + k] * invE - mu1 * mu1;
        float a1   = g1[k] * rsqrtf(var1 + 1e-5f);
        float c1   = beta1[k] - mu1 * a1;
        float sI   = yv[(size_t)row * 64 + k] + zv[(size_t)ic * 64 + k] + b1[k];
        float hh   = fmaf(sI, a1, c1);
        hh = hh > 0.f ? hh : 0.f;
        accv = fmaf(hh, W2[ch * 64 + k], accv);
      }
      float v = accv + b2[ch];
      if (a2 >= 0.f) h = v > h ? v : h; else h = v < h ? v : h;
    }
  }
  float o = (cnt[row] > 0) ? fmaf(h, a2, c2) : 0.0f;
  outp[idx] = o > 0.f ? o : 0.f;
}

// --------------------------------------------------------------- launch ----
extern "C" void kernel_launch(void* const* d_in, const int* in_sizes, int n_in,
                              void* d_out, int out_size, void* d_ws, size_t ws_size,
                              hipStream_t stream) {
  (void)in_sizes; (void)n_in; (void)out_size; (void)ws_size;
  const float* x     = (const float*)d_in[0];
  const float* pos   = (const float*)d_in[1];
  const float* W1    = (const float*)d_in[3];
  const float* b1    = (const float*)d_in[4];
  const float* g1    = (const float*)d_in[5];
  const float* beta1 = (const float*)d_in[6];
  const float* W2    = (const float*)d_in[7];
  const float* b2    = (const float*)d_in[8];
  const float* g2    = (const float*)d_in[9];
  const float* beta2 = (const float*)d_in[10];
  float* outp = (float*)d_out;

  char* w = (char*)d_ws;
  int*   nbr     = (int*)w;                            // 1,310,720 B
  float* yv      = (float*)(w + 1310720);              // 4,194,304 B
  float* zv      = (float*)(w + 5505024);              // 4,194,304 B
  float* stats   = (float*)(w + 9699328);              // 1,024 B
  int*   cnt     = (int*)(w + 9700352);                // 65,536 B
  int*   ovf_cnt = (int*)(w + 9765888);                // 64 B
  int*   ovf     = (int*)(w + 9765952);                // 32,768 B
  int*   rev     = (int*)(w + 9798720);                // 8,388,608 B -> 18,187,328
  float* mmax    = (float*)(w + 18187328);             // 4,194,304 B
  float* mmin    = (float*)(w + 22381632);             // 4,194,304 B -> 26,575,936

  hipMemsetAsync(stats, 0, 1024, stream);
  hipMemsetAsync(cnt, 0, 65536 + 64, stream);

  knn_kernel<<<NPT / 16, 256, 0, stream>>>(pos, nbr, cnt, ovf_cnt, ovf, rev);
  node_gemm<<<NPT / 4, 256, 0, stream>>>(x, W1, yv, zv);
  bn1_stats<<<NPT / 16, 256, 0, stream>>>(nbr, (const float4*)yv, (const float4*)zv, b1, stats);
  gemm2_row<<<NPT / 16, 256, 0, stream>>>(
      (const float4*)yv, (const float4*)zv, b1, stats, g1, beta1, W2, b2,
      cnt, rev, stats + 128, mmax, mmin);
  finalize_out<<<NPT * 64 / 256, 256, 0, stream>>>(
      stats + 128, g2, beta2, cnt, mmax, mmin, ovf_cnt, ovf, nbr,
      yv, zv, b1, stats, g1, beta1, W2, b2, outp);
}

// Round 12
// 235.789 us; speedup vs baseline: 1.0789x; 1.0223x over previous
//
#include <hip/hip_runtime.h>

constexpr int BATCH = 8;
constexpr int PPC   = 2048;            // points per cloud
constexpr int NPT   = BATCH * PPC;     // 16384 points
constexpr int OCH   = 64;              // out channels (= in channels)
constexpr int KNN_K = 20;
constexpr int NEDGE = NPT * KNN_K;     // 327680 edges
constexpr int REVCAP = 128;            // per-row reverse-adjacency capacity
constexpr int OVCAP  = 8192;           // overflow list capacity
constexpr int QCAP   = 48;             // per-point qualifier capacity

typedef short short8 __attribute__((ext_vector_type(8)));
typedef float float4v __attribute__((ext_vector_type(4)));

__device__ __forceinline__ unsigned short bfr(float f) {  // f32 -> bf16 RNE
  unsigned u = __float_as_uint(f);
  return (unsigned short)((u + 0x7FFFu + ((u >> 16) & 1u)) >> 16);
}
__device__ __forceinline__ short8 pack8(float4 a, float4 b) {
  short8 r;
  r[0] = (short)bfr(a.x); r[1] = (short)bfr(a.y);
  r[2] = (short)bfr(a.z); r[3] = (short)bfr(a.w);
  r[4] = (short)bfr(b.x); r[5] = (short)bfr(b.y);
  r[6] = (short)bfr(b.z); r[7] = (short)bfr(b.w);
  return r;
}
__device__ __forceinline__ unsigned umed3(unsigned a, unsigned b, unsigned c) {
  unsigned d;
  asm("v_med3_u32 %0, %1, %2, %3" : "=v"(d) : "v"(a), "v"(b), "v"(c));
  return d;
}

// ---------------------------------------------------------------- kNN ------
// Block = 16 points x 16 splits (256 threads). Top-3-per-lane bound T',
// qualifier push, exact (d2,index) rank. rev[] stores CENTER index.
__global__ __launch_bounds__(256) void knn_kernel(const float* __restrict__ pos,
                                                  int* __restrict__ nbr,
                                                  int* __restrict__ cnt,
                                                  int* __restrict__ ovf_cnt,
                                                  int* __restrict__ ovf,
                                                  int* __restrict__ rev) {
  __shared__ float4 cps[8 * 257];                 // region r at r*257 (+pad)
  __shared__ unsigned long long qk[16][QCAP];     // per-point qualifiers
  __shared__ int qn[16];
  const int t  = threadIdx.x;
  const int pl = t >> 4;                     // point-local 0..15
  const int s  = t & 15;                     // split 0..15
  const int lane = t & 63;
  const int i  = blockIdx.x * 16 + pl;
  const int cbase = i & ~(PPC - 1);

  for (int u = t; u < PPC; u += 256) {
    int j = cbase + u;
    float ax = pos[3 * j], ay = pos[3 * j + 1], az = pos[3 * j + 2];
    cps[(u >> 8) * 257 + (u & 255)] = make_float4(ax, ay, az, ax * ax + ay * ay + az * az);
  }
  if (t < 16) qn[t] = 0;
  __syncthreads();

  const int il = i - cbase;
  const float4 me = cps[(il >> 8) * 257 + (il & 255)];
  const float px = me.x, py = me.y, pz = me.z, sqi = me.w;
  const int jbase = s * 128;
  const float4* __restrict__ cp = &cps[(s >> 1) * 257 + (s & 1) * 128];

  unsigned kd[3];
  kd[0] = kd[1] = kd[2] = 0xFFFFFFFFu;
  for (int u = 0; u < 128; ++u) {
    float4 c = cp[u];
    float d2 = sqi + c.w - 2.0f * (px * c.x + py * c.y + pz * c.z);
    d2 = d2 > 0.f ? d2 : 0.f;
    unsigned ck = __float_as_uint(d2);
    ck = (jbase + u == il) ? 0xFFFFFFFFu : ck;
    kd[2] = umed3(kd[1], kd[2], ck);
    kd[1] = umed3(kd[0], kd[1], ck);
    kd[0] = kd[0] < ck ? kd[0] : ck;
  }

  unsigned T = 0xFFFFFFFFu;
  int cum = 0;
  const int grp = lane & 48;
#pragma unroll
  for (int r = 0; r < KNN_K; ++r) {
    unsigned w = kd[0];
#pragma unroll
    for (int m = 1; m < 16; m <<= 1) {
      unsigned o = (unsigned)__shfl_xor((int)w, m, 16);
      w = o < w ? o : w;
    }
    bool pop = (kd[0] == w);
    unsigned long long bal = __ballot(pop);
    int mcount = __popc((int)((bal >> grp) & 0xFFFFull));
    if (cum < KNN_K) T = w;
    cum += mcount;
    if (pop) { kd[0] = kd[1]; kd[1] = kd[2]; kd[2] = 0xFFFFFFFFu; }
  }

  for (int u = 0; u < 128; ++u) {
    float4 c = cp[u];
    float d2 = sqi + c.w - 2.0f * (px * c.x + py * c.y + pz * c.z);
    d2 = d2 > 0.f ? d2 : 0.f;
    unsigned ck = __float_as_uint(d2);
    ck = (jbase + u == il) ? 0xFFFFFFFFu : ck;
    if (ck <= T) {
      int slot = atomicAdd(&qn[pl], 1);
      if (slot < QCAP)
        qk[pl][slot] = ((unsigned long long)ck << 32) | (unsigned)(jbase + u);
    }
  }
  __syncthreads();

  int n = qn[pl]; n = n < QCAP ? n : QCAP;
  for (int base = 0; base < n; base += 16) {
    int e = base + s;
    if (e < n) {
      unsigned long long mk = qk[pl][e];
      int rank = 0;
      for (int o = 0; o < n; ++o) rank += (qk[pl][o] < mk) ? 1 : 0;
      if (rank < KNN_K) {
        int j = cbase + (int)(mk & 0xFFFFFFFFull);
        int eid = i * KNN_K + rank;
        nbr[eid] = j;
        int slot = atomicAdd(&cnt[j], 1);
        if (slot < REVCAP) rev[j * REVCAP + slot] = i;   // center index
        else { int ov = atomicAdd(ovf_cnt, 1); if (ov < OVCAP) ovf[ov] = eid; }
      }
    }
  }
}

// ------------------------------------------------- node-level layer-1 GEMM -
__global__ __launch_bounds__(256) void node_gemm(const float* __restrict__ x,
                                                 const float* __restrict__ W1,
                                                 float* __restrict__ yv,
                                                 float* __restrict__ zv) {
  __shared__ float wa[64][65];
  __shared__ float wb[64][65];
  __shared__ float xs[4][64];
  const int t = threadIdx.x;
  for (int m = t; m < 8192; m += 256) {
    int o = m >> 7, c2 = m & 127;
    float w = W1[m];
    if (c2 < 64) wa[c2][o] = w; else wb[c2 - 64][o] = w;
  }
  const int nl = t >> 6, o = t & 63;
  xs[nl][o] = x[(size_t)(blockIdx.x * 4 + nl) * 64 + o];
  __syncthreads();
  float accA = 0.f, accB = 0.f;
#pragma unroll 8
  for (int c = 0; c < 64; ++c) {
    float xv = xs[nl][c];
    accA = fmaf(xv, wa[c][o], accA);
    accB = fmaf(xv, wb[c][o], accB);
  }
  size_t n = (size_t)blockIdx.x * 4 + nl;
  yv[n * 64 + o] = accA - accB;
  zv[n * 64 + o] = accB;
}

// ---------------------------- BN1 stats: center-grouped (z once, 20 y rows) -
__global__ __launch_bounds__(256) void bn1_stats(const int* __restrict__ nbr,
                                                 const float4* __restrict__ yv4,
                                                 const float4* __restrict__ zv4,
                                                 const float* __restrict__ b1,
                                                 float* __restrict__ stats) {
  const int t  = threadIdx.x;
  const int c4 = t & 15;
  const int lane = t & 63;
  const int i  = blockIdx.x * 16 + (t >> 4);
  const float4 bo = reinterpret_cast<const float4*>(b1)[c4];
  float4 z = zv4[(size_t)i * 16 + c4];
  float4 zb = make_float4(z.x + bo.x, z.y + bo.y, z.z + bo.z, z.w + bo.w);
  int jA = nbr[i * KNN_K + c4];
  int jB = nbr[i * KNN_K + 16 + (c4 & 3)];
  float4 s1 = make_float4(0, 0, 0, 0), s2 = make_float4(0, 0, 0, 0);
#pragma unroll
  for (int q = 0; q < 16; ++q) {
    int j = __shfl(jA, (lane & 48) + q);
    float4 y = yv4[(size_t)j * 16 + c4];
    float sx = y.x + zb.x, sy = y.y + zb.y, sz = y.z + zb.z, sw = y.w + zb.w;
    s1.x += sx; s1.y += sy; s1.z += sz; s1.w += sw;
    s2.x += sx * sx; s2.y += sy * sy; s2.z += sz * sz; s2.w += sw * sw;
  }
#pragma unroll
  for (int q = 0; q < 4; ++q) {
    int j = __shfl(jB, (lane & 48) + q);
    float4 y = yv4[(size_t)j * 16 + c4];
    float sx = y.x + zb.x, sy = y.y + zb.y, sz = y.z + zb.z, sw = y.w + zb.w;
    s1.x += sx; s1.y += sy; s1.z += sz; s1.w += sw;
    s2.x += sx * sx; s2.y += sy * sy; s2.z += sz * sz; s2.w += sw * sw;
  }
  s1.x += __shfl_xor(s1.x, 16); s1.y += __shfl_xor(s1.y, 16);
  s1.z += __shfl_xor(s1.z, 16); s1.w += __shfl_xor(s1.w, 16);
  s2.x += __shfl_xor(s2.x, 16); s2.y += __shfl_xor(s2.y, 16);
  s2.z += __shfl_xor(s2.z, 16); s2.w += __shfl_xor(s2.w, 16);
  s1.x += __shfl_xor(s1.x, 32); s1.y += __shfl_xor(s1.y, 32);
  s1.z += __shfl_xor(s1.z, 32); s1.w += __shfl_xor(s1.w, 32);
  s2.x += __shfl_xor(s2.x, 32); s2.y += __shfl_xor(s2.y, 32);
  s2.z += __shfl_xor(s2.z, 32); s2.w += __shfl_xor(s2.w, 32);
  __shared__ float ss[2][64];
  if (t < 128) { ss[0][t & 63] = 0.f; }
  __syncthreads();
  if ((t & 48) == 0) {
    atomicAdd(&ss[0][c4 * 4 + 0], s1.x); atomicAdd(&ss[0][c4 * 4 + 1], s1.y);
    atomicAdd(&ss[0][c4 * 4 + 2], s1.z); atomicAdd(&ss[0][c4 * 4 + 3], s1.w);
    atomicAdd(&ss[1][c4 * 4 + 0], s2.x); atomicAdd(&ss[1][c4 * 4 + 1], s2.y);
    atomicAdd(&ss[1][c4 * 4 + 2], s2.z); atomicAdd(&ss[1][c4 * 4 + 3], s2.w);
  }
  __syncthreads();
  if (t < 64)       atomicAdd(&stats[t], ss[0][t]);
  else if (t < 128) atomicAdd(&stats[64 + (t - 64)], ss[1][t - 64]);
}

// ----------- per-wave row-owned GEMM2 (bf16 MFMA), all-register A-path -----
// One wave owns 4 rows. Lane (col,quad) builds its A-fragment directly in
// registers: edge = ti*16+col, channels quad*8..+7 (af0) and 32+quad*8..+7
// (af1) -- 4 float4 z-gathers + y regs + folded BN1 affine + bf16 pack.
// No LDS, no barriers, no waitcnts in the hot loop; tiles are independent.
__global__ __launch_bounds__(256) void gemm2_row(
    const float4* __restrict__ yv4, const float4* __restrict__ zv4,
    const float* __restrict__ b1, const float* __restrict__ stats1,
    const float* __restrict__ g1, const float* __restrict__ beta1,
    const float* __restrict__ W2, const float* __restrict__ b2,
    const int* __restrict__ cnt, const int* __restrict__ rev,
    float* __restrict__ stats2, float* __restrict__ mmax,
    float* __restrict__ mmin) {
  __shared__ float ss[2][64];
  const int t = threadIdx.x, lane = t & 63;
  const int col = lane & 15, quad = lane >> 4;
  const int wid = blockIdx.x * 4 + (t >> 6);
  constexpr float invE = 1.0f / NEDGE;

  // folded BN1 coefs for this lane's 16 channels: h = (y+z)*a1 + c1p, relu
  float a1r[16], c1r[16];
#pragma unroll
  for (int half = 0; half < 2; ++half)
#pragma unroll
    for (int q = 0; q < 8; ++q) {
      int ch = half * 32 + quad * 8 + q;
      float mu  = stats1[ch] * invE;
      float var = stats1[64 + ch] * invE - mu * mu;
      float a   = g1[ch] * rsqrtf(var + 1e-5f);
      a1r[half * 8 + q] = a;
      c1r[half * 8 + q] = fmaf(b1[ch], a, beta1[ch] - mu * a);
    }
  // W2 B-fragments into registers
  short8 bf0[4], bf1[4];
  const float4* __restrict__ W2v = (const float4*)W2;
#pragma unroll
  for (int nt = 0; nt < 4; ++nt) {
    int row = nt * 16 + col;
    float4 wa = W2v[row * 16 + quad * 2];
    float4 wb = W2v[row * 16 + quad * 2 + 1];
    float4 wc = W2v[row * 16 + 8 + quad * 2];
    float4 wd = W2v[row * 16 + 8 + quad * 2 + 1];
    bf0[nt] = pack8(wa, wb);
    bf1[nt] = pack8(wc, wd);
  }
  float b2r[4];
#pragma unroll
  for (int nt = 0; nt < 4; ++nt) b2r[nt] = b2[nt * 16 + col];

  float s1[4] = {0, 0, 0, 0}, s2[4] = {0, 0, 0, 0};
  for (int row = wid * 4; row < wid * 4 + 4; ++row) {
    int n = cnt[row]; n = n < REVCAP ? n : REVCAP;
    int rv0 = (lane < n) ? rev[(size_t)row * REVCAP + lane] : 0;
    int rv1 = (64 + lane < n) ? rev[(size_t)row * REVCAP + 64 + lane] : 0;
    // y for this lane's 16 channels
    float4 ya = yv4[(size_t)row * 16 + quad * 2];
    float4 yb = yv4[(size_t)row * 16 + quad * 2 + 1];
    float4 yc = yv4[(size_t)row * 16 + 8 + quad * 2];
    float4 yd = yv4[(size_t)row * 16 + 8 + quad * 2 + 1];
    float mx[4], mn[4];
#pragma unroll
    for (int nt = 0; nt < 4; ++nt) { mx[nt] = -1e30f; mn[nt] = 1e30f; }
    const int ntile = (n + 15) >> 4;
    for (int ti = 0; ti < ntile; ++ti) {
      int gi = ti * 16 + col;                  // this lane's A-fragment edge
      int v0 = __shfl(rv0, gi & 63);
      int v1 = __shfl(rv1, gi & 63);
      int ic = (gi < 64) ? v0 : v1;
      ic = (gi < n) ? ic : 0;
      float4 za = zv4[(size_t)ic * 16 + quad * 2];
      float4 zb = zv4[(size_t)ic * 16 + quad * 2 + 1];
      float4 zc = zv4[(size_t)ic * 16 + 8 + quad * 2];
      float4 zd = zv4[(size_t)ic * 16 + 8 + quad * 2 + 1];
      float h[16];
      h[0]  = fmaf(ya.x + za.x, a1r[0],  c1r[0]);
      h[1]  = fmaf(ya.y + za.y, a1r[1],  c1r[1]);
      h[2]  = fmaf(ya.z + za.z, a1r[2],  c1r[2]);
      h[3]  = fmaf(ya.w + za.w, a1r[3],  c1r[3]);
      h[4]  = fmaf(yb.x + zb.x, a1r[4],  c1r[4]);
      h[5]  = fmaf(yb.y + zb.y, a1r[5],  c1r[5]);
      h[6]  = fmaf(yb.z + zb.z, a1r[6],  c1r[6]);
      h[7]  = fmaf(yb.w + zb.w, a1r[7],  c1r[7]);
      h[8]  = fmaf(yc.x + zc.x, a1r[8],  c1r[8]);
      h[9]  = fmaf(yc.y + zc.y, a1r[9],  c1r[9]);
      h[10] = fmaf(yc.z + zc.z, a1r[10], c1r[10]);
      h[11] = fmaf(yc.w + zc.w, a1r[11], c1r[11]);
      h[12] = fmaf(yd.x + zd.x, a1r[12], c1r[12]);
      h[13] = fmaf(yd.y + zd.y, a1r[13], c1r[13]);
      h[14] = fmaf(yd.z + zd.z, a1r[14], c1r[14]);
      h[15] = fmaf(yd.w + zd.w, a1r[15], c1r[15]);
      short8 af0, af1;
#pragma unroll
      for (int q = 0; q < 8; ++q) {
        float u0 = h[q]     > 0.f ? h[q]     : 0.f;
        float u1 = h[8 + q] > 0.f ? h[8 + q] : 0.f;
        af0[q] = (short)bfr(u0);
        af1[q] = (short)bfr(u1);
      }
      float4v acc[4];
#pragma unroll
      for (int nt = 0; nt < 4; ++nt) {
        acc[nt] = (float4v){0.f, 0.f, 0.f, 0.f};
        acc[nt] = __builtin_amdgcn_mfma_f32_16x16x32_bf16(af0, bf0[nt], acc[nt], 0, 0, 0);
        acc[nt] = __builtin_amdgcn_mfma_f32_16x16x32_bf16(af1, bf1[nt], acc[nt], 0, 0, 0);
      }
      // D: edge = ti*16 + quad*4 + r, channel = nt*16 + col
#pragma unroll
      for (int r = 0; r < 4; ++r) {
        bool v = (ti * 16 + quad * 4 + r) < n;
#pragma unroll
        for (int nt = 0; nt < 4; ++nt) {
          float val = acc[nt][r] + b2r[nt];
          if (v) {
            s1[nt] += val; s2[nt] += val * val;
            mx[nt] = val > mx[nt] ? val : mx[nt];
            mn[nt] = val < mn[nt] ? val : mn[nt];
          }
        }
      }
    }
#pragma unroll
    for (int nt = 0; nt < 4; ++nt) {
      mx[nt] = fmaxf(mx[nt], __shfl_xor(mx[nt], 16));
      mx[nt] = fmaxf(mx[nt], __shfl_xor(mx[nt], 32));
      mn[nt] = fminf(mn[nt], __shfl_xor(mn[nt], 16));
      mn[nt] = fminf(mn[nt], __shfl_xor(mn[nt], 32));
    }
    if (quad == 0) {
#pragma unroll
      for (int nt = 0; nt < 4; ++nt) {
        mmax[(size_t)row * 64 + nt * 16 + col] = mx[nt];
        mmin[(size_t)row * 64 + nt * 16 + col] = mn[nt];
      }
    }
  }
  // block-level stats reduction
  if (t < 128) ss[t >> 6][t & 63] = 0.f;
  __syncthreads();
#pragma unroll
  for (int nt = 0; nt < 4; ++nt) {
    s1[nt] += __shfl_xor(s1[nt], 16);
    s1[nt] += __shfl_xor(s1[nt], 32);
    s2[nt] += __shfl_xor(s2[nt], 16);
    s2[nt] += __shfl_xor(s2[nt], 32);
  }
  if (quad == 0) {
#pragma unroll
    for (int nt = 0; nt < 4; ++nt) {
      atomicAdd(&ss[0][nt * 16 + col], s1[nt]);
      atomicAdd(&ss[1][nt * 16 + col], s2[nt]);
    }
  }
  __syncthreads();
  if (t < 64)       atomicAdd(&stats2[t], ss[0][t]);
  else if (t < 128) atomicAdd(&stats2[64 + (t - 64)], ss[1][t - 64]);
}

// ---------------- finalize: BN2 affine of per-row max/min + relu + empties -
__global__ __launch_bounds__(256) void finalize_out(
    const float* __restrict__ stats2, const float* __restrict__ g2,
    const float* __restrict__ beta2, const int* __restrict__ cnt,
    const float* __restrict__ mmax, const float* __restrict__ mmin,
    const int* __restrict__ ovf_cnt, const int* __restrict__ ovf,
    const int* __restrict__ nbr, const float* __restrict__ yv,
    const float* __restrict__ zv, const float* __restrict__ b1,
    const float* __restrict__ stats1, const float* __restrict__ g1,
    const float* __restrict__ beta1, const float* __restrict__ W2,
    const float* __restrict__ b2, float* __restrict__ outp) {
  const int idx = blockIdx.x * 256 + threadIdx.x;
  const int row = idx >> 6, ch = idx & 63;
  constexpr float invE = 1.0f / NEDGE;
  float mu  = stats2[ch] * invE;
  float var = stats2[64 + ch] * invE - mu * mu;
  float a2  = g2[ch] * rsqrtf(var + 1e-5f);
  float c2  = beta2[ch] - mu * a2;
  float h = (a2 >= 0.f) ? mmax[idx] : mmin[idx];
  int ov = ovf_cnt[0]; ov = ov > OVCAP ? OVCAP : ov;
  for (int u = 0; u < ov; ++u) {
    int e = ovf[u];
    if (nbr[e] == row) {
      int ic = e / KNN_K;
      float accv = 0.f;
      for (int k = 0; k < 64; ++k) {
        float mu1  = stats1[k] * invE;
        float var1 = stats1[64 + k] * invE - mu1 * mu1;
        float a1   = g1[k] * rsqrtf(var1 + 1e-5f);
        float c1   = beta1[k] - mu1 * a1;
        float sI   = yv[(size_t)row * 64 + k] + zv[(size_t)ic * 64 + k] + b1[k];
        float hh   = fmaf(sI, a1, c1);
        hh = hh > 0.f ? hh : 0.f;
        accv = fmaf(hh, W2[ch * 64 + k], accv);
      }
      float v = accv + b2[ch];
      if (a2 >= 0.f) h = v > h ? v : h; else h = v < h ? v : h;
    }
  }
  float o = (cnt[row] > 0) ? fmaf(h, a2, c2) : 0.0f;
  outp[idx] = o > 0.f ? o : 0.f;
}

// --------------------------------------------------------------- launch ----
extern "C" void kernel_launch(void* const* d_in, const int* in_sizes, int n_in,
                              void* d_out, int out_size, void* d_ws, size_t ws_size,
                              hipStream_t stream) {
  (void)in_sizes; (void)n_in; (void)out_size; (void)ws_size;
  const float* x     = (const float*)d_in[0];
  const float* pos   = (const float*)d_in[1];
  const float* W1    = (const float*)d_in[3];
  const float* b1    = (const float*)d_in[4];
  const float* g1    = (const float*)d_in[5];
  const float* beta1 = (const float*)d_in[6];
  const float* W2    = (const float*)d_in[7];
  const float* b2    = (const float*)d_in[8];
  const float* g2    = (const float*)d_in[9];
  const float* beta2 = (const float*)d_in[10];
  float* outp = (float*)d_out;

  char* w = (char*)d_ws;
  int*   nbr     = (int*)w;                            // 1,310,720 B
  float* yv      = (float*)(w + 1310720);              // 4,194,304 B
  float* zv      = (float*)(w + 5505024);              // 4,194,304 B
  float* stats   = (float*)(w + 9699328);              // 1,024 B
  int*   cnt     = (int*)(w + 9700352);                // 65,536 B
  int*   ovf_cnt = (int*)(w + 9765888);                // 64 B
  int*   ovf     = (int*)(w + 9765952);                // 32,768 B
  int*   rev     = (int*)(w + 9798720);                // 8,388,608 B -> 18,187,328
  float* mmax    = (float*)(w + 18187328);             // 4,194,304 B
  float* mmin    = (float*)(w + 22381632);             // 4,194,304 B -> 26,575,936

  hipMemsetAsync(stats, 0, 1024, stream);
  hipMemsetAsync(cnt, 0, 65536 + 64, stream);

  knn_kernel<<<NPT / 16, 256, 0, stream>>>(pos, nbr, cnt, ovf_cnt, ovf, rev);
  node_gemm<<<NPT / 4, 256, 0, stream>>>(x, W1, yv, zv);
  bn1_stats<<<NPT / 16, 256, 0, stream>>>(nbr, (const float4*)yv, (const float4*)zv, b1, stats);
  gemm2_row<<<NPT / 16, 256, 0, stream>>>(
      (const float4*)yv, (const float4*)zv, b1, stats, g1, beta1, W2, b2,
      cnt, rev, stats + 128, mmax, mmin);
  finalize_out<<<NPT * 64 / 256, 256, 0, stream>>>(
      stats + 128, g2, beta2, cnt, mmax, mmin, ovf_cnt, ovf, nbr,
      yv, zv, b1, stats, g1, beta1, W2, b2, outp);
}

// Round 13
// 234.394 us; speedup vs baseline: 1.0853x; 1.0059x over previous
//
#include <hip/hip_runtime.h>

constexpr int BATCH = 8;
constexpr int PPC   = 2048;            // points per cloud
constexpr int NPT   = BATCH * PPC;     // 16384 points
constexpr int OCH   = 64;              // out channels (= in channels)
constexpr int KNN_K = 20;
constexpr int NEDGE = NPT * KNN_K;     // 327680 edges
constexpr int REVCAP = 128;            // per-row reverse-adjacency capacity
constexpr int OVCAP  = 8192;           // overflow list capacity
constexpr int QCAP   = 48;             // per-point qualifier capacity

typedef short short8 __attribute__((ext_vector_type(8)));
typedef float float4v __attribute__((ext_vector_type(4)));

__device__ __forceinline__ unsigned short bfr(float f) {  // f32 -> bf16 RNE
  unsigned u = __float_as_uint(f);
  return (unsigned short)((u + 0x7FFFu + ((u >> 16) & 1u)) >> 16);
}
__device__ __forceinline__ short8 pack8(float4 a, float4 b) {
  short8 r;
  r[0] = (short)bfr(a.x); r[1] = (short)bfr(a.y);
  r[2] = (short)bfr(a.z); r[3] = (short)bfr(a.w);
  r[4] = (short)bfr(b.x); r[5] = (short)bfr(b.y);
  r[6] = (short)bfr(b.z); r[7] = (short)bfr(b.w);
  return r;
}
__device__ __forceinline__ unsigned umed3(unsigned a, unsigned b, unsigned c) {
  unsigned d;
  asm("v_med3_u32 %0, %1, %2, %3" : "=v"(d) : "v"(a), "v"(b), "v"(c));
  return d;
}

// ---------------------------------------------------------------- kNN ------
__global__ __launch_bounds__(256) void knn_kernel(const float* __restrict__ pos,
                                                  int* __restrict__ nbr,
                                                  int* __restrict__ cnt,
                                                  int* __restrict__ ovf_cnt,
                                                  int* __restrict__ ovf,
                                                  int* __restrict__ rev) {
  __shared__ float4 cps[8 * 257];                 // region r at r*257 (+pad)
  __shared__ unsigned long long qk[16][QCAP];     // per-point qualifiers
  __shared__ int qn[16];
  const int t  = threadIdx.x;
  const int pl = t >> 4;                     // point-local 0..15
  const int s  = t & 15;                     // split 0..15
  const int lane = t & 63;
  const int i  = blockIdx.x * 16 + pl;
  const int cbase = i & ~(PPC - 1);

  for (int u = t; u < PPC; u += 256) {
    int j = cbase + u;
    float ax = pos[3 * j], ay = pos[3 * j + 1], az = pos[3 * j + 2];
    cps[(u >> 8) * 257 + (u & 255)] = make_float4(ax, ay, az, ax * ax + ay * ay + az * az);
  }
  if (t < 16) qn[t] = 0;
  __syncthreads();

  const int il = i - cbase;
  const float4 me = cps[(il >> 8) * 257 + (il & 255)];
  const float px = me.x, py = me.y, pz = me.z, sqi = me.w;
  const int jbase = s * 128;
  const float4* __restrict__ cp = &cps[(s >> 1) * 257 + (s & 1) * 128];

  unsigned kd[3];
  kd[0] = kd[1] = kd[2] = 0xFFFFFFFFu;
  for (int u = 0; u < 128; ++u) {
    float4 c = cp[u];
    float d2 = sqi + c.w - 2.0f * (px * c.x + py * c.y + pz * c.z);
    d2 = d2 > 0.f ? d2 : 0.f;
    unsigned ck = __float_as_uint(d2);
    ck = (jbase + u == il) ? 0xFFFFFFFFu : ck;
    kd[2] = umed3(kd[1], kd[2], ck);
    kd[1] = umed3(kd[0], kd[1], ck);
    kd[0] = kd[0] < ck ? kd[0] : ck;
  }

  unsigned T = 0xFFFFFFFFu;
  int cum = 0;
  const int grp = lane & 48;
#pragma unroll
  for (int r = 0; r < KNN_K; ++r) {
    unsigned w = kd[0];
#pragma unroll
    for (int m = 1; m < 16; m <<= 1) {
      unsigned o = (unsigned)__shfl_xor((int)w, m, 16);
      w = o < w ? o : w;
    }
    bool pop = (kd[0] == w);
    unsigned long long bal = __ballot(pop);
    int mcount = __popc((int)((bal >> grp) & 0xFFFFull));
    if (cum < KNN_K) T = w;
    cum += mcount;
    if (pop) { kd[0] = kd[1]; kd[1] = kd[2]; kd[2] = 0xFFFFFFFFu; }
  }

  for (int u = 0; u < 128; ++u) {
    float4 c = cp[u];
    float d2 = sqi + c.w - 2.0f * (px * c.x + py * c.y + pz * c.z);
    d2 = d2 > 0.f ? d2 : 0.f;
    unsigned ck = __float_as_uint(d2);
    ck = (jbase + u == il) ? 0xFFFFFFFFu : ck;
    if (ck <= T) {
      int slot = atomicAdd(&qn[pl], 1);
      if (slot < QCAP)
        qk[pl][slot] = ((unsigned long long)ck << 32) | (unsigned)(jbase + u);
    }
  }
  __syncthreads();

  int n = qn[pl]; n = n < QCAP ? n : QCAP;
  for (int base = 0; base < n; base += 16) {
    int e = base + s;
    if (e < n) {
      unsigned long long mk = qk[pl][e];
      int rank = 0;
      for (int o = 0; o < n; ++o) rank += (qk[pl][o] < mk) ? 1 : 0;
      if (rank < KNN_K) {
        int j = cbase + (int)(mk & 0xFFFFFFFFull);
        int eid = i * KNN_K + rank;
        nbr[eid] = j;
        int slot = atomicAdd(&cnt[j], 1);
        if (slot < REVCAP) rev[j * REVCAP + slot] = i;   // center index
        else { int ov = atomicAdd(ovf_cnt, 1); if (ov < OVCAP) ovf[ov] = eid; }
      }
    }
  }
}

// ------------------------------------------------- node-level layer-1 GEMM -
__global__ __launch_bounds__(256) void node_gemm(const float* __restrict__ x,
                                                 const float* __restrict__ W1,
                                                 float* __restrict__ yv,
                                                 float* __restrict__ zv) {
  __shared__ float wa[64][65];
  __shared__ float wb[64][65];
  __shared__ float xs[4][64];
  const int t = threadIdx.x;
  for (int m = t; m < 8192; m += 256) {
    int o = m >> 7, c2 = m & 127;
    float w = W1[m];
    if (c2 < 64) wa[c2][o] = w; else wb[c2 - 64][o] = w;
  }
  const int nl = t >> 6, o = t & 63;
  xs[nl][o] = x[(size_t)(blockIdx.x * 4 + nl) * 64 + o];
  __syncthreads();
  float accA = 0.f, accB = 0.f;
#pragma unroll 8
  for (int c = 0; c < 64; ++c) {
    float xv = xs[nl][c];
    accA = fmaf(xv, wa[c][o], accA);
    accB = fmaf(xv, wb[c][o], accB);
  }
  size_t n = (size_t)blockIdx.x * 4 + nl;
  yv[n * 64 + o] = accA - accB;
  zv[n * 64 + o] = accB;
}

// ---------------------------- BN1 stats: center-grouped (z once, 20 y rows) -
__global__ __launch_bounds__(256) void bn1_stats(const int* __restrict__ nbr,
                                                 const float4* __restrict__ yv4,
                                                 const float4* __restrict__ zv4,
                                                 const float* __restrict__ b1,
                                                 float* __restrict__ stats) {
  const int t  = threadIdx.x;
  const int c4 = t & 15;
  const int lane = t & 63;
  const int i  = blockIdx.x * 16 + (t >> 4);
  const float4 bo = reinterpret_cast<const float4*>(b1)[c4];
  float4 z = zv4[(size_t)i * 16 + c4];
  float4 zb = make_float4(z.x + bo.x, z.y + bo.y, z.z + bo.z, z.w + bo.w);
  int jA = nbr[i * KNN_K + c4];
  int jB = nbr[i * KNN_K + 16 + (c4 & 3)];
  float4 s1 = make_float4(0, 0, 0, 0), s2 = make_float4(0, 0, 0, 0);
#pragma unroll
  for (int q = 0; q < 16; ++q) {
    int j = __shfl(jA, (lane & 48) + q);
    float4 y = yv4[(size_t)j * 16 + c4];
    float sx = y.x + zb.x, sy = y.y + zb.y, sz = y.z + zb.z, sw = y.w + zb.w;
    s1.x += sx; s1.y += sy; s1.z += sz; s1.w += sw;
    s2.x += sx * sx; s2.y += sy * sy; s2.z += sz * sz; s2.w += sw * sw;
  }
#pragma unroll
  for (int q = 0; q < 4; ++q) {
    int j = __shfl(jB, (lane & 48) + q);
    float4 y = yv4[(size_t)j * 16 + c4];
    float sx = y.x + zb.x, sy = y.y + zb.y, sz = y.z + zb.z, sw = y.w + zb.w;
    s1.x += sx; s1.y += sy; s1.z += sz; s1.w += sw;
    s2.x += sx * sx; s2.y += sy * sy; s2.z += sz * sz; s2.w += sw * sw;
  }
  s1.x += __shfl_xor(s1.x, 16); s1.y += __shfl_xor(s1.y, 16);
  s1.z += __shfl_xor(s1.z, 16); s1.w += __shfl_xor(s1.w, 16);
  s2.x += __shfl_xor(s2.x, 16); s2.y += __shfl_xor(s2.y, 16);
  s2.z += __shfl_xor(s2.z, 16); s2.w += __shfl_xor(s2.w, 16);
  s1.x += __shfl_xor(s1.x, 32); s1.y += __shfl_xor(s1.y, 32);
  s1.z += __shfl_xor(s1.z, 32); s1.w += __shfl_xor(s1.w, 32);
  s2.x += __shfl_xor(s2.x, 32); s2.y += __shfl_xor(s2.y, 32);
  s2.z += __shfl_xor(s2.z, 32); s2.w += __shfl_xor(s2.w, 32);
  __shared__ float ss[2][64];
  if (t < 128) { ss[0][t & 63] = 0.f; }
  __syncthreads();
  if ((t & 48) == 0) {
    atomicAdd(&ss[0][c4 * 4 + 0], s1.x); atomicAdd(&ss[0][c4 * 4 + 1], s1.y);
    atomicAdd(&ss[0][c4 * 4 + 2], s1.z); atomicAdd(&ss[0][c4 * 4 + 3], s1.w);
    atomicAdd(&ss[1][c4 * 4 + 0], s2.x); atomicAdd(&ss[1][c4 * 4 + 1], s2.y);
    atomicAdd(&ss[1][c4 * 4 + 2], s2.z); atomicAdd(&ss[1][c4 * 4 + 3], s2.w);
  }
  __syncthreads();
  if (t < 64)       atomicAdd(&stats[t], ss[0][t]);
  else if (t < 128) atomicAdd(&stats[64 + (t - 64)], ss[1][t - 64]);
}

// ------------- pre-apply BN1: Ys = y*a1 ; Zs = z*a1 + (b1*a1 + c1) ---------
__global__ __launch_bounds__(256) void scale_yz(
    const float4* __restrict__ yv4, const float4* __restrict__ zv4,
    const float* __restrict__ stats1, const float* __restrict__ g1,
    const float* __restrict__ beta1, const float* __restrict__ b1,
    float4* __restrict__ ys4, float4* __restrict__ zs4) {
  const int idx = blockIdx.x * 256 + threadIdx.x;   // over NPT*16
  const int c4 = idx & 15;
  constexpr float invE = 1.0f / NEDGE;
  float a[4], c[4];
#pragma unroll
  for (int q = 0; q < 4; ++q) {
    int ch = c4 * 4 + q;
    float mu  = stats1[ch] * invE;
    float var = stats1[64 + ch] * invE - mu * mu;
    float av  = g1[ch] * rsqrtf(var + 1e-5f);
    a[q] = av;
    c[q] = fmaf(b1[ch], av, beta1[ch] - mu * av);
  }
  float4 y = yv4[idx];
  float4 z = zv4[idx];
  ys4[idx] = make_float4(y.x * a[0], y.y * a[1], y.z * a[2], y.w * a[3]);
  zs4[idx] = make_float4(fmaf(z.x, a[0], c[0]), fmaf(z.y, a[1], c[1]),
                         fmaf(z.z, a[2], c[2]), fmaf(z.w, a[3], c[3]));
}

// ----------- per-wave row-owned GEMM2 (bf16 MFMA), 2-tile pipelined --------
// One wave owns 4 rows. h1 = relu(Ys[row] + Zs[ic]) built in registers.
// Both tiles' z-gathers issued before tile-0 compute (ILP); tail loop for
// rare rows with n>32. No LDS / barriers / waitcnts in the hot path.
__global__ __launch_bounds__(256) void gemm2_row(
    const float4* __restrict__ ys4, const float4* __restrict__ zs4,
    const float* __restrict__ W2, const float* __restrict__ b2,
    const int* __restrict__ cnt, const int* __restrict__ rev,
    float* __restrict__ stats2, float* __restrict__ mmax,
    float* __restrict__ mmin) {
  __shared__ float ss[2][64];
  const int t = threadIdx.x, lane = t & 63;
  const int col = lane & 15, quad = lane >> 4;
  const int wid = blockIdx.x * 4 + (t >> 6);

  // W2 B-fragments into registers
  short8 bf0[4], bf1[4];
  const float4* __restrict__ W2v = (const float4*)W2;
#pragma unroll
  for (int nt = 0; nt < 4; ++nt) {
    int row = nt * 16 + col;
    float4 wa = W2v[row * 16 + quad * 2];
    float4 wb = W2v[row * 16 + quad * 2 + 1];
    float4 wc = W2v[row * 16 + 8 + quad * 2];
    float4 wd = W2v[row * 16 + 8 + quad * 2 + 1];
    bf0[nt] = pack8(wa, wb);
    bf1[nt] = pack8(wc, wd);
  }
  float b2r[4];
#pragma unroll
  for (int nt = 0; nt < 4; ++nt) b2r[nt] = b2[nt * 16 + col];

  float s1[4] = {0, 0, 0, 0}, s2[4] = {0, 0, 0, 0};
  for (int rr = 0; rr < 4; ++rr) {
    const int row = wid * 4 + rr;
    int n = cnt[row]; n = n < REVCAP ? n : REVCAP;
    int rv0 = (lane < n) ? rev[(size_t)row * REVCAP + lane] : 0;
    int rv1 = (64 + lane < n) ? rev[(size_t)row * REVCAP + 64 + lane] : 0;
    float4 ya = ys4[(size_t)row * 16 + quad * 2];
    float4 yb = ys4[(size_t)row * 16 + quad * 2 + 1];
    float4 yc = ys4[(size_t)row * 16 + 8 + quad * 2];
    float4 yd = ys4[(size_t)row * 16 + 8 + quad * 2 + 1];
    float mx[4], mn[4];
#pragma unroll
    for (int nt = 0; nt < 4; ++nt) { mx[nt] = -1e30f; mn[nt] = 1e30f; }

    auto tile_body = [&](int tbase, float4 za, float4 zb, float4 zc, float4 zd) {
      float h[16];
      h[0]  = ya.x + za.x; h[1]  = ya.y + za.y; h[2]  = ya.z + za.z; h[3]  = ya.w + za.w;
      h[4]  = yb.x + zb.x; h[5]  = yb.y + zb.y; h[6]  = yb.z + zb.z; h[7]  = yb.w + zb.w;
      h[8]  = yc.x + zc.x; h[9]  = yc.y + zc.y; h[10] = yc.z + zc.z; h[11] = yc.w + zc.w;
      h[12] = yd.x + zd.x; h[13] = yd.y + zd.y; h[14] = yd.z + zd.z; h[15] = yd.w + zd.w;
      short8 af0, af1;
#pragma unroll
      for (int q = 0; q < 8; ++q) {
        float u0 = h[q]     > 0.f ? h[q]     : 0.f;
        float u1 = h[8 + q] > 0.f ? h[8 + q] : 0.f;
        af0[q] = (short)bfr(u0);
        af1[q] = (short)bfr(u1);
      }
      float4v acc[4];
#pragma unroll
      for (int nt = 0; nt < 4; ++nt) {
        acc[nt] = (float4v){0.f, 0.f, 0.f, 0.f};
        acc[nt] = __builtin_amdgcn_mfma_f32_16x16x32_bf16(af0, bf0[nt], acc[nt], 0, 0, 0);
        acc[nt] = __builtin_amdgcn_mfma_f32_16x16x32_bf16(af1, bf1[nt], acc[nt], 0, 0, 0);
      }
#pragma unroll
      for (int r = 0; r < 4; ++r) {
        bool v = (tbase + quad * 4 + r) < n;
#pragma unroll
        for (int nt = 0; nt < 4; ++nt) {
          float val = acc[nt][r] + b2r[nt];
          if (v) {
            s1[nt] += val; s2[nt] += val * val;
            mx[nt] = val > mx[nt] ? val : mx[nt];
            mn[nt] = val < mn[nt] ? val : mn[nt];
          }
        }
      }
    };

    // tiles 0 and 1: issue all gathers first, then compute
    int icA = __shfl(rv0, col);       icA = (col < n) ? icA : 0;
    int icB = __shfl(rv0, 16 + col);  icB = (16 + col < n) ? icB : 0;
    float4 zAa = zs4[(size_t)icA * 16 + quad * 2];
    float4 zAb = zs4[(size_t)icA * 16 + quad * 2 + 1];
    float4 zAc = zs4[(size_t)icA * 16 + 8 + quad * 2];
    float4 zAd = zs4[(size_t)icA * 16 + 8 + quad * 2 + 1];
    float4 zBa = zs4[(size_t)icB * 16 + quad * 2];
    float4 zBb = zs4[(size_t)icB * 16 + quad * 2 + 1];
    float4 zBc = zs4[(size_t)icB * 16 + 8 + quad * 2];
    float4 zBd = zs4[(size_t)icB * 16 + 8 + quad * 2 + 1];
    tile_body(0, zAa, zAb, zAc, zAd);
    if (n > 16) tile_body(16, zBa, zBb, zBc, zBd);
    // rare tail: rows with n > 32
    for (int ti = 2; ti * 16 < n; ++ti) {
      int gi = ti * 16 + col;
      int v0 = __shfl(rv0, gi & 63);
      int v1 = __shfl(rv1, gi & 63);
      int ic = (gi < 64) ? v0 : v1;
      ic = (gi < n) ? ic : 0;
      float4 za = zs4[(size_t)ic * 16 + quad * 2];
      float4 zb = zs4[(size_t)ic * 16 + quad * 2 + 1];
      float4 zc = zs4[(size_t)ic * 16 + 8 + quad * 2];
      float4 zd = zs4[(size_t)ic * 16 + 8 + quad * 2 + 1];
      tile_body(ti * 16, za, zb, zc, zd);
    }
#pragma unroll
    for (int nt = 0; nt < 4; ++nt) {
      mx[nt] = fmaxf(mx[nt], __shfl_xor(mx[nt], 16));
      mx[nt] = fmaxf(mx[nt], __shfl_xor(mx[nt], 32));
      mn[nt] = fminf(mn[nt], __shfl_xor(mn[nt], 16));
      mn[nt] = fminf(mn[nt], __shfl_xor(mn[nt], 32));
    }
    if (quad == 0) {
#pragma unroll
      for (int nt = 0; nt < 4; ++nt) {
        mmax[(size_t)row * 64 + nt * 16 + col] = mx[nt];
        mmin[(size_t)row * 64 + nt * 16 + col] = mn[nt];
      }
    }
  }
  // block-level stats reduction
  if (t < 128) ss[t >> 6][t & 63] = 0.f;
  __syncthreads();
#pragma unroll
  for (int nt = 0; nt < 4; ++nt) {
    s1[nt] += __shfl_xor(s1[nt], 16);
    s1[nt] += __shfl_xor(s1[nt], 32);
    s2[nt] += __shfl_xor(s2[nt], 16);
    s2[nt] += __shfl_xor(s2[nt], 32);
  }
  if (quad == 0) {
#pragma unroll
    for (int nt = 0; nt < 4; ++nt) {
      atomicAdd(&ss[0][nt * 16 + col], s1[nt]);
      atomicAdd(&ss[1][nt * 16 + col], s2[nt]);
    }
  }
  __syncthreads();
  if (t < 64)       atomicAdd(&stats2[t], ss[0][t]);
  else if (t < 128) atomicAdd(&stats2[64 + (t - 64)], ss[1][t - 64]);
}

// ---------------- finalize: BN2 affine of per-row max/min + relu + empties -
__global__ __launch_bounds__(256) void finalize_out(
    const float* __restrict__ stats2, const float* __restrict__ g2,
    const float* __restrict__ beta2, const int* __restrict__ cnt,
    const float* __restrict__ mmax, const float* __restrict__ mmin,
    const int* __restrict__ ovf_cnt, const int* __restrict__ ovf,
    const int* __restrict__ nbr, const float* __restrict__ ys,
    const float* __restrict__ zs, const float* __restrict__ W2,
    const float* __restrict__ b2, float* __restrict__ outp) {
  const int idx = blockIdx.x * 256 + threadIdx.x;
  const int row = idx >> 6, ch = idx & 63;
  constexpr float invE = 1.0f / NEDGE;
  float mu  = stats2[ch] * invE;
  float var = stats2[64 + ch] * invE - mu * mu;
  float a2  = g2[ch] * rsqrtf(var + 1e-5f);
  float c2  = beta2[ch] - mu * a2;
  float h = (a2 >= 0.f) ? mmax[idx] : mmin[idx];
  int ov = ovf_cnt[0]; ov = ov > OVCAP ? OVCAP : ov;
  for (int u = 0; u < ov; ++u) {
    int e = ovf[u];
    if (nbr[e] == row) {
      int ic = e / KNN_K;
      float accv = 0.f;
      for (int k = 0; k < 64; ++k) {
        float hh = ys[(size_t)row * 64 + k] + zs[(size_t)ic * 64 + k];
        hh = hh > 0.f ? hh : 0.f;
        accv = fmaf(hh, W2[ch * 64 + k], accv);
      }
      float v = accv + b2[ch];
      if (a2 >= 0.f) h = v > h ? v : h; else h = v < h ? v : h;
    }
  }
  float o = (cnt[row] > 0) ? fmaf(h, a2, c2) : 0.0f;
  outp[idx] = o > 0.f ? o : 0.f;
}

// --------------------------------------------------------------- launch ----
extern "C" void kernel_launch(void* const* d_in, const int* in_sizes, int n_in,
                              void* d_out, int out_size, void* d_ws, size_t ws_size,
                              hipStream_t stream) {
  (void)in_sizes; (void)n_in; (void)out_size; (void)ws_size;
  const float* x     = (const float*)d_in[0];
  const float* pos   = (const float*)d_in[1];
  const float* W1    = (const float*)d_in[3];
  const float* b1    = (const float*)d_in[4];
  const float* g1    = (const float*)d_in[5];
  const float* beta1 = (const float*)d_in[6];
  const float* W2    = (const float*)d_in[7];
  const float* b2    = (const float*)d_in[8];
  const float* g2    = (const float*)d_in[9];
  const float* beta2 = (const float*)d_in[10];
  float* outp = (float*)d_out;

  char* w = (char*)d_ws;
  int*   nbr     = (int*)w;                            // 1,310,720 B
  float* yv      = (float*)(w + 1310720);              // 4,194,304 B
  float* zv      = (float*)(w + 5505024);              // 4,194,304 B
  float* stats   = (float*)(w + 9699328);              // 1,024 B
  int*   cnt     = (int*)(w + 9700352);                // 65,536 B
  int*   ovf_cnt = (int*)(w + 9765888);                // 64 B
  int*   ovf     = (int*)(w + 9765952);                // 32,768 B
  int*   rev     = (int*)(w + 9798720);                // 8,388,608 B -> 18,187,328
  float* mmax    = (float*)(w + 18187328);             // 4,194,304 B
  float* mmin    = (float*)(w + 22381632);             // 4,194,304 B -> 26,575,936
  float* ys      = (float*)(w + 26575936);             // 4,194,304 B
  float* zs      = (float*)(w + 30770240);             // 4,194,304 B -> 34,964,544

  hipMemsetAsync(stats, 0, 1024, stream);
  hipMemsetAsync(cnt, 0, 65536 + 64, stream);

  knn_kernel<<<NPT / 16, 256, 0, stream>>>(pos, nbr, cnt, ovf_cnt, ovf, rev);
  node_gemm<<<NPT / 4, 256, 0, stream>>>(x, W1, yv, zv);
  bn1_stats<<<NPT / 16, 256, 0, stream>>>(nbr, (const float4*)yv, (const float4*)zv, b1, stats);
  scale_yz<<<NPT * 16 / 256, 256, 0, stream>>>(
      (const float4*)yv, (const float4*)zv, stats, g1, beta1, b1,
      (float4*)ys, (float4*)zs);
  gemm2_row<<<NPT / 16, 256, 0, stream>>>(
      (const float4*)ys, (const float4*)zs, W2, b2,
      cnt, rev, stats + 128, mmax, mmin);
  finalize_out<<<NPT * 64 / 256, 256, 0, stream>>>(
      stats + 128, g2, beta2, cnt, mmax, mmin, ovf_cnt, ovf, nbr,
      ys, zs, W2, b2, outp);
}

// Round 14
// 231.472 us; speedup vs baseline: 1.0990x; 1.0126x over previous
//
#include <hip/hip_runtime.h>

constexpr int BATCH = 8;
constexpr int PPC   = 2048;            // points per cloud
constexpr int NPT   = BATCH * PPC;     // 16384 points
constexpr int OCH   = 64;              // out channels (= in channels)
constexpr int KNN_K = 20;
constexpr int NEDGE = NPT * KNN_K;     // 327680 edges
constexpr int REVCAP = 128;            // per-row reverse-adjacency capacity
constexpr int OVCAP  = 8192;           // overflow list capacity
constexpr int QCAP   = 48;             // per-point qualifier capacity

typedef short short8 __attribute__((ext_vector_type(8)));
typedef float float4v __attribute__((ext_vector_type(4)));

// XCD-aware swizzle: blocks of one cloud all land on one XCD
// (hardware maps blockIdx % 8 -> XCD; cloud c's blocks get b%8==c).
__device__ __forceinline__ int xcd_swizzle(int b, int nper) {
  return (b & 7) * nper + (b >> 3);
}

__device__ __forceinline__ unsigned short bfr(float f) {  // f32 -> bf16 RNE
  unsigned u = __float_as_uint(f);
  return (unsigned short)((u + 0x7FFFu + ((u >> 16) & 1u)) >> 16);
}
__device__ __forceinline__ short8 pack8(float4 a, float4 b) {
  short8 r;
  r[0] = (short)bfr(a.x); r[1] = (short)bfr(a.y);
  r[2] = (short)bfr(a.z); r[3] = (short)bfr(a.w);
  r[4] = (short)bfr(b.x); r[5] = (short)bfr(b.y);
  r[6] = (short)bfr(b.z); r[7] = (short)bfr(b.w);
  return r;
}
__device__ __forceinline__ unsigned umed3(unsigned a, unsigned b, unsigned c) {
  unsigned d;
  asm("v_med3_u32 %0, %1, %2, %3" : "=v"(d) : "v"(a), "v"(b), "v"(c));
  return d;
}

// ---------------------------------------------------------------- kNN ------
__global__ __launch_bounds__(256) void knn_kernel(const float* __restrict__ pos,
                                                  int* __restrict__ nbr,
                                                  int* __restrict__ cnt,
                                                  int* __restrict__ ovf_cnt,
                                                  int* __restrict__ ovf,
                                                  int* __restrict__ rev) {
  __shared__ float4 cps[8 * 257];                 // region r at r*257 (+pad)
  __shared__ unsigned long long qk[16][QCAP];     // per-point qualifiers
  __shared__ int qn[16];
  const int t  = threadIdx.x;
  const int pl = t >> 4;                     // point-local 0..15
  const int s  = t & 15;                     // split 0..15
  const int lane = t & 63;
  const int eb = xcd_swizzle(blockIdx.x, NPT / 16 / 8);
  const int i  = eb * 16 + pl;
  const int cbase = i & ~(PPC - 1);

  for (int u = t; u < PPC; u += 256) {
    int j = cbase + u;
    float ax = pos[3 * j], ay = pos[3 * j + 1], az = pos[3 * j + 2];
    cps[(u >> 8) * 257 + (u & 255)] = make_float4(ax, ay, az, ax * ax + ay * ay + az * az);
  }
  if (t < 16) qn[t] = 0;
  __syncthreads();

  const int il = i - cbase;
  const float4 me = cps[(il >> 8) * 257 + (il & 255)];
  const float px = me.x, py = me.y, pz = me.z, sqi = me.w;
  const int jbase = s * 128;
  const float4* __restrict__ cp = &cps[(s >> 1) * 257 + (s & 1) * 128];

  unsigned kd[3];
  kd[0] = kd[1] = kd[2] = 0xFFFFFFFFu;
  for (int u = 0; u < 128; ++u) {
    float4 c = cp[u];
    float d2 = sqi + c.w - 2.0f * (px * c.x + py * c.y + pz * c.z);
    d2 = d2 > 0.f ? d2 : 0.f;
    unsigned ck = __float_as_uint(d2);
    ck = (jbase + u == il) ? 0xFFFFFFFFu : ck;
    kd[2] = umed3(kd[1], kd[2], ck);
    kd[1] = umed3(kd[0], kd[1], ck);
    kd[0] = kd[0] < ck ? kd[0] : ck;
  }

  unsigned T = 0xFFFFFFFFu;
  int cum = 0;
  const int grp = lane & 48;
#pragma unroll
  for (int r = 0; r < KNN_K; ++r) {
    unsigned w = kd[0];
#pragma unroll
    for (int m = 1; m < 16; m <<= 1) {
      unsigned o = (unsigned)__shfl_xor((int)w, m, 16);
      w = o < w ? o : w;
    }
    bool pop = (kd[0] == w);
    unsigned long long bal = __ballot(pop);
    int mcount = __popc((int)((bal >> grp) & 0xFFFFull));
    if (cum < KNN_K) T = w;
    cum += mcount;
    if (pop) { kd[0] = kd[1]; kd[1] = kd[2]; kd[2] = 0xFFFFFFFFu; }
  }

  for (int u = 0; u < 128; ++u) {
    float4 c = cp[u];
    float d2 = sqi + c.w - 2.0f * (px * c.x + py * c.y + pz * c.z);
    d2 = d2 > 0.f ? d2 : 0.f;
    unsigned ck = __float_as_uint(d2);
    ck = (jbase + u == il) ? 0xFFFFFFFFu : ck;
    if (ck <= T) {
      int slot = atomicAdd(&qn[pl], 1);
      if (slot < QCAP)
        qk[pl][slot] = ((unsigned long long)ck << 32) | (unsigned)(jbase + u);
    }
  }
  __syncthreads();

  int n = qn[pl]; n = n < QCAP ? n : QCAP;
  for (int base = 0; base < n; base += 16) {
    int e = base + s;
    if (e < n) {
      unsigned long long mk = qk[pl][e];
      int rank = 0;
      for (int o = 0; o < n; ++o) rank += (qk[pl][o] < mk) ? 1 : 0;
      if (rank < KNN_K) {
        int j = cbase + (int)(mk & 0xFFFFFFFFull);
        int eid = i * KNN_K + rank;
        nbr[eid] = j;
        int slot = atomicAdd(&cnt[j], 1);
        if (slot < REVCAP) rev[j * REVCAP + slot] = i;   // center index
        else { int ov = atomicAdd(ovf_cnt, 1); if (ov < OVCAP) ovf[ov] = eid; }
      }
    }
  }
}

// ------------------------------------------------- node-level layer-1 GEMM -
__global__ __launch_bounds__(256) void node_gemm(const float* __restrict__ x,
                                                 const float* __restrict__ W1,
                                                 float* __restrict__ yv,
                                                 float* __restrict__ zv) {
  __shared__ float wa[64][65];
  __shared__ float wb[64][65];
  __shared__ float xs[4][64];
  const int t = threadIdx.x;
  for (int m = t; m < 8192; m += 256) {
    int o = m >> 7, c2 = m & 127;
    float w = W1[m];
    if (c2 < 64) wa[c2][o] = w; else wb[c2 - 64][o] = w;
  }
  const int nl = t >> 6, o = t & 63;
  xs[nl][o] = x[(size_t)(blockIdx.x * 4 + nl) * 64 + o];
  __syncthreads();
  float accA = 0.f, accB = 0.f;
#pragma unroll 8
  for (int c = 0; c < 64; ++c) {
    float xv = xs[nl][c];
    accA = fmaf(xv, wa[c][o], accA);
    accB = fmaf(xv, wb[c][o], accB);
  }
  size_t n = (size_t)blockIdx.x * 4 + nl;
  yv[n * 64 + o] = accA - accB;
  zv[n * 64 + o] = accB;
}

// ---------------------------- BN1 stats: center-grouped (z once, 20 y rows) -
__global__ __launch_bounds__(256) void bn1_stats(const int* __restrict__ nbr,
                                                 const float4* __restrict__ yv4,
                                                 const float4* __restrict__ zv4,
                                                 const float* __restrict__ b1,
                                                 float* __restrict__ stats) {
  const int t  = threadIdx.x;
  const int c4 = t & 15;
  const int lane = t & 63;
  const int eb = xcd_swizzle(blockIdx.x, NPT / 16 / 8);
  const int i  = eb * 16 + (t >> 4);
  const float4 bo = reinterpret_cast<const float4*>(b1)[c4];
  float4 z = zv4[(size_t)i * 16 + c4];
  float4 zb = make_float4(z.x + bo.x, z.y + bo.y, z.z + bo.z, z.w + bo.w);
  int jA = nbr[i * KNN_K + c4];
  int jB = nbr[i * KNN_K + 16 + (c4 & 3)];
  float4 s1 = make_float4(0, 0, 0, 0), s2 = make_float4(0, 0, 0, 0);
#pragma unroll
  for (int q = 0; q < 16; ++q) {
    int j = __shfl(jA, (lane & 48) + q);
    float4 y = yv4[(size_t)j * 16 + c4];
    float sx = y.x + zb.x, sy = y.y + zb.y, sz = y.z + zb.z, sw = y.w + zb.w;
    s1.x += sx; s1.y += sy; s1.z += sz; s1.w += sw;
    s2.x += sx * sx; s2.y += sy * sy; s2.z += sz * sz; s2.w += sw * sw;
  }
#pragma unroll
  for (int q = 0; q < 4; ++q) {
    int j = __shfl(jB, (lane & 48) + q);
    float4 y = yv4[(size_t)j * 16 + c4];
    float sx = y.x + zb.x, sy = y.y + zb.y, sz = y.z + zb.z, sw = y.w + zb.w;
    s1.x += sx; s1.y += sy; s1.z += sz; s1.w += sw;
    s2.x += sx * sx; s2.y += sy * sy; s2.z += sz * sz; s2.w += sw * sw;
  }
  s1.x += __shfl_xor(s1.x, 16); s1.y += __shfl_xor(s1.y, 16);
  s1.z += __shfl_xor(s1.z, 16); s1.w += __shfl_xor(s1.w, 16);
  s2.x += __shfl_xor(s2.x, 16); s2.y += __shfl_xor(s2.y, 16);
  s2.z += __shfl_xor(s2.z, 16); s2.w += __shfl_xor(s2.w, 16);
  s1.x += __shfl_xor(s1.x, 32); s1.y += __shfl_xor(s1.y, 32);
  s1.z += __shfl_xor(s1.z, 32); s1.w += __shfl_xor(s1.w, 32);
  s2.x += __shfl_xor(s2.x, 32); s2.y += __shfl_xor(s2.y, 32);
  s2.z += __shfl_xor(s2.z, 32); s2.w += __shfl_xor(s2.w, 32);
  __shared__ float ss[2][64];
  if (t < 128) { ss[0][t & 63] = 0.f; }
  __syncthreads();
  if ((t & 48) == 0) {
    atomicAdd(&ss[0][c4 * 4 + 0], s1.x); atomicAdd(&ss[0][c4 * 4 + 1], s1.y);
    atomicAdd(&ss[0][c4 * 4 + 2], s1.z); atomicAdd(&ss[0][c4 * 4 + 3], s1.w);
    atomicAdd(&ss[1][c4 * 4 + 0], s2.x); atomicAdd(&ss[1][c4 * 4 + 1], s2.y);
    atomicAdd(&ss[1][c4 * 4 + 2], s2.z); atomicAdd(&ss[1][c4 * 4 + 3], s2.w);
  }
  __syncthreads();
  if (t < 64)       atomicAdd(&stats[t], ss[0][t]);
  else if (t < 128) atomicAdd(&stats[64 + (t - 64)], ss[1][t - 64]);
}

// ------------- pre-apply BN1: Ys = y*a1 ; Zs = z*a1 + (b1*a1 + c1) ---------
__global__ __launch_bounds__(256) void scale_yz(
    const float4* __restrict__ yv4, const float4* __restrict__ zv4,
    const float* __restrict__ stats1, const float* __restrict__ g1,
    const float* __restrict__ beta1, const float* __restrict__ b1,
    float4* __restrict__ ys4, float4* __restrict__ zs4) {
  const int idx = blockIdx.x * 256 + threadIdx.x;   // over NPT*16
  const int c4 = idx & 15;
  constexpr float invE = 1.0f / NEDGE;
  float a[4], c[4];
#pragma unroll
  for (int q = 0; q < 4; ++q) {
    int ch = c4 * 4 + q;
    float mu  = stats1[ch] * invE;
    float var = stats1[64 + ch] * invE - mu * mu;
    float av  = g1[ch] * rsqrtf(var + 1e-5f);
    a[q] = av;
    c[q] = fmaf(b1[ch], av, beta1[ch] - mu * av);
  }
  float4 y = yv4[idx];
  float4 z = zv4[idx];
  ys4[idx] = make_float4(y.x * a[0], y.y * a[1], y.z * a[2], y.w * a[3]);
  zs4[idx] = make_float4(fmaf(z.x, a[0], c[0]), fmaf(z.y, a[1], c[1]),
                         fmaf(z.z, a[2], c[2]), fmaf(z.w, a[3], c[3]));
}

// ----------- per-wave row-owned GEMM2 (bf16 MFMA), 2-tile pipelined --------
__global__ __launch_bounds__(256) void gemm2_row(
    const float4* __restrict__ ys4, const float4* __restrict__ zs4,
    const float* __restrict__ W2, const float* __restrict__ b2,
    const int* __restrict__ cnt, const int* __restrict__ rev,
    float* __restrict__ stats2, float* __restrict__ mmax,
    float* __restrict__ mmin) {
  __shared__ float ss[2][64];
  const int t = threadIdx.x, lane = t & 63;
  const int col = lane & 15, quad = lane >> 4;
  const int eb = xcd_swizzle(blockIdx.x, NPT / 16 / 8);
  const int wid = eb * 4 + (t >> 6);

  // W2 B-fragments into registers
  short8 bf0[4], bf1[4];
  const float4* __restrict__ W2v = (const float4*)W2;
#pragma unroll
  for (int nt = 0; nt < 4; ++nt) {
    int row = nt * 16 + col;
    float4 wa = W2v[row * 16 + quad * 2];
    float4 wb = W2v[row * 16 + quad * 2 + 1];
    float4 wc = W2v[row * 16 + 8 + quad * 2];
    float4 wd = W2v[row * 16 + 8 + quad * 2 + 1];
    bf0[nt] = pack8(wa, wb);
    bf1[nt] = pack8(wc, wd);
  }
  float b2r[4];
#pragma unroll
  for (int nt = 0; nt < 4; ++nt) b2r[nt] = b2[nt * 16 + col];

  float s1[4] = {0, 0, 0, 0}, s2[4] = {0, 0, 0, 0};
  for (int rr = 0; rr < 4; ++rr) {
    const int row = wid * 4 + rr;
    int n = cnt[row]; n = n < REVCAP ? n : REVCAP;
    int rv0 = (lane < n) ? rev[(size_t)row * REVCAP + lane] : 0;
    int rv1 = (64 + lane < n) ? rev[(size_t)row * REVCAP + 64 + lane] : 0;
    float4 ya = ys4[(size_t)row * 16 + quad * 2];
    float4 yb = ys4[(size_t)row * 16 + quad * 2 + 1];
    float4 yc = ys4[(size_t)row * 16 + 8 + quad * 2];
    float4 yd = ys4[(size_t)row * 16 + 8 + quad * 2 + 1];
    float mx[4], mn[4];
#pragma unroll
    for (int nt = 0; nt < 4; ++nt) { mx[nt] = -1e30f; mn[nt] = 1e30f; }

    auto tile_body = [&](int tbase, float4 za, float4 zb, float4 zc, float4 zd) {
      float h[16];
      h[0]  = ya.x + za.x; h[1]  = ya.y + za.y; h[2]  = ya.z + za.z; h[3]  = ya.w + za.w;
      h[4]  = yb.x + zb.x; h[5]  = yb.y + zb.y; h[6]  = yb.z + zb.z; h[7]  = yb.w + zb.w;
      h[8]  = yc.x + zc.x; h[9]  = yc.y + zc.y; h[10] = yc.z + zc.z; h[11] = yc.w + zc.w;
      h[12] = yd.x + zd.x; h[13] = yd.y + zd.y; h[14] = yd.z + zd.z; h[15] = yd.w + zd.w;
      short8 af0, af1;
#pragma unroll
      for (int q = 0; q < 8; ++q) {
        float u0 = h[q]     > 0.f ? h[q]     : 0.f;
        float u1 = h[8 + q] > 0.f ? h[8 + q] : 0.f;
        af0[q] = (short)bfr(u0);
        af1[q] = (short)bfr(u1);
      }
      float4v acc[4];
#pragma unroll
      for (int nt = 0; nt < 4; ++nt) {
        acc[nt] = (float4v){0.f, 0.f, 0.f, 0.f};
        acc[nt] = __builtin_amdgcn_mfma_f32_16x16x32_bf16(af0, bf0[nt], acc[nt], 0, 0, 0);
        acc[nt] = __builtin_amdgcn_mfma_f32_16x16x32_bf16(af1, bf1[nt], acc[nt], 0, 0, 0);
      }
#pragma unroll
      for (int r = 0; r < 4; ++r) {
        bool v = (tbase + quad * 4 + r) < n;
#pragma unroll
        for (int nt = 0; nt < 4; ++nt) {
          float val = acc[nt][r] + b2r[nt];
          if (v) {
            s1[nt] += val; s2[nt] += val * val;
            mx[nt] = val > mx[nt] ? val : mx[nt];
            mn[nt] = val < mn[nt] ? val : mn[nt];
          }
        }
      }
    };

    // tiles 0 and 1: issue all gathers first, then compute
    int icA = __shfl(rv0, col);       icA = (col < n) ? icA : 0;
    int icB = __shfl(rv0, 16 + col);  icB = (16 + col < n) ? icB : 0;
    float4 zAa = zs4[(size_t)icA * 16 + quad * 2];
    float4 zAb = zs4[(size_t)icA * 16 + quad * 2 + 1];
    float4 zAc = zs4[(size_t)icA * 16 + 8 + quad * 2];
    float4 zAd = zs4[(size_t)icA * 16 + 8 + quad * 2 + 1];
    float4 zBa = zs4[(size_t)icB * 16 + quad * 2];
    float4 zBb = zs4[(size_t)icB * 16 + quad * 2 + 1];
    float4 zBc = zs4[(size_t)icB * 16 + 8 + quad * 2];
    float4 zBd = zs4[(size_t)icB * 16 + 8 + quad * 2 + 1];
    tile_body(0, zAa, zAb, zAc, zAd);
    if (n > 16) tile_body(16, zBa, zBb, zBc, zBd);
    for (int ti = 2; ti * 16 < n; ++ti) {
      int gi = ti * 16 + col;
      int v0 = __shfl(rv0, gi & 63);
      int v1 = __shfl(rv1, gi & 63);
      int ic = (gi < 64) ? v0 : v1;
      ic = (gi < n) ? ic : 0;
      float4 za = zs4[(size_t)ic * 16 + quad * 2];
      float4 zb = zs4[(size_t)ic * 16 + quad * 2 + 1];
      float4 zc = zs4[(size_t)ic * 16 + 8 + quad * 2];
      float4 zd = zs4[(size_t)ic * 16 + 8 + quad * 2 + 1];
      tile_body(ti * 16, za, zb, zc, zd);
    }
#pragma unroll
    for (int nt = 0; nt < 4; ++nt) {
      mx[nt] = fmaxf(mx[nt], __shfl_xor(mx[nt], 16));
      mx[nt] = fmaxf(mx[nt], __shfl_xor(mx[nt], 32));
      mn[nt] = fminf(mn[nt], __shfl_xor(mn[nt], 16));
      mn[nt] = fminf(mn[nt], __shfl_xor(mn[nt], 32));
    }
    if (quad == 0) {
#pragma unroll
      for (int nt = 0; nt < 4; ++nt) {
        mmax[(size_t)row * 64 + nt * 16 + col] = mx[nt];
        mmin[(size_t)row * 64 + nt * 16 + col] = mn[nt];
      }
    }
  }
  // block-level stats reduction
  if (t < 128) ss[t >> 6][t & 63] = 0.f;
  __syncthreads();
#pragma unroll
  for (int nt = 0; nt < 4; ++nt) {
    s1[nt] += __shfl_xor(s1[nt], 16);
    s1[nt] += __shfl_xor(s1[nt], 32);
    s2[nt] += __shfl_xor(s2[nt], 16);
    s2[nt] += __shfl_xor(s2[nt], 32);
  }
  if (quad == 0) {
#pragma unroll
    for (int nt = 0; nt < 4; ++nt) {
      atomicAdd(&ss[0][nt * 16 + col], s1[nt]);
      atomicAdd(&ss[1][nt * 16 + col], s2[nt]);
    }
  }
  __syncthreads();
  if (t < 64)       atomicAdd(&stats2[t], ss[0][t]);
  else if (t < 128) atomicAdd(&stats2[64 + (t - 64)], ss[1][t - 64]);
}

// ---------------- finalize: BN2 affine of per-row max/min + relu + empties -
__global__ __launch_bounds__(256) void finalize_out(
    const float* __restrict__ stats2, const float* __restrict__ g2,
    const float* __restrict__ beta2, const int* __restrict__ cnt,
    const float* __restrict__ mmax, const float* __restrict__ mmin,
    const int* __restrict__ ovf_cnt, const int* __restrict__ ovf,
    const int* __restrict__ nbr, const float* __restrict__ ys,
    const float* __restrict__ zs, const float* __restrict__ W2,
    const float* __restrict__ b2, float* __restrict__ outp) {
  const int idx = blockIdx.x * 256 + threadIdx.x;
  const int row = idx >> 6, ch = idx & 63;
  constexpr float invE = 1.0f / NEDGE;
  float mu  = stats2[ch] * invE;
  float var = stats2[64 + ch] * invE - mu * mu;
  float a2  = g2[ch] * rsqrtf(var + 1e-5f);
  float c2  = beta2[ch] - mu * a2;
  float h = (a2 >= 0.f) ? mmax[idx] : mmin[idx];
  int ov = ovf_cnt[0]; ov = ov > OVCAP ? OVCAP : ov;
  for (int u = 0; u < ov; ++u) {
    int e = ovf[u];
    if (nbr[e] == row) {
      int ic = e / KNN_K;
      float accv = 0.f;
      for (int k = 0; k < 64; ++k) {
        float hh = ys[(size_t)row * 64 + k] + zs[(size_t)ic * 64 + k];
        hh = hh > 0.f ? hh : 0.f;
        accv = fmaf(hh, W2[ch * 64 + k], accv);
      }
      float v = accv + b2[ch];
      if (a2 >= 0.f) h = v > h ? v : h; else h = v < h ? v : h;
    }
  }
  float o = (cnt[row] > 0) ? fmaf(h, a2, c2) : 0.0f;
  outp[idx] = o > 0.f ? o : 0.f;
}

// --------------------------------------------------------------- launch ----
extern "C" void kernel_launch(void* const* d_in, const int* in_sizes, int n_in,
                              void* d_out, int out_size, void* d_ws, size_t ws_size,
                              hipStream_t stream) {
  (void)in_sizes; (void)n_in; (void)out_size; (void)ws_size;
  const float* x     = (const float*)d_in[0];
  const float* pos   = (const float*)d_in[1];
  const float* W1    = (const float*)d_in[3];
  const float* b1    = (const float*)d_in[4];
  const float* g1    = (const float*)d_in[5];
  const float* beta1 = (const float*)d_in[6];
  const float* W2    = (const float*)d_in[7];
  const float* b2    = (const float*)d_in[8];
  const float* g2    = (const float*)d_in[9];
  const float* beta2 = (const float*)d_in[10];
  float* outp = (float*)d_out;

  char* w = (char*)d_ws;
  int*   nbr     = (int*)w;                            // 1,310,720 B
  float* yv      = (float*)(w + 1310720);              // 4,194,304 B
  float* zv      = (float*)(w + 5505024);              // 4,194,304 B
  float* stats   = (float*)(w + 9699328);              // 1,024 B
  int*   cnt     = (int*)(w + 9700352);                // 65,536 B
  int*   ovf_cnt = (int*)(w + 9765888);                // 64 B
  int*   ovf     = (int*)(w + 9765952);                // 32,768 B
  int*   rev     = (int*)(w + 9798720);                // 8,388,608 B -> 18,187,328
  float* mmax    = (float*)(w + 18187328);             // 4,194,304 B
  float* mmin    = (float*)(w + 22381632);             // 4,194,304 B -> 26,575,936
  float* ys      = (float*)(w + 26575936);             // 4,194,304 B
  float* zs      = (float*)(w + 30770240);             // 4,194,304 B -> 34,964,544

  hipMemsetAsync(stats, 0, 1024, stream);
  hipMemsetAsync(cnt, 0, 65536 + 64, stream);

  knn_kernel<<<NPT / 16, 256, 0, stream>>>(pos, nbr, cnt, ovf_cnt, ovf, rev);
  node_gemm<<<NPT / 4, 256, 0, stream>>>(x, W1, yv, zv);
  bn1_stats<<<NPT / 16, 256, 0, stream>>>(nbr, (const float4*)yv, (const float4*)zv, b1, stats);
  scale_yz<<<NPT * 16 / 256, 256, 0, stream>>>(
      (const float4*)yv, (const float4*)zv, stats, g1, beta1, b1,
      (float4*)ys, (float4*)zs);
  gemm2_row<<<NPT / 16, 256, 0, stream>>>(
      (const float4*)ys, (const float4*)zs, W2, b2,
      cnt, rev, stats + 128, mmax, mmin);
  finalize_out<<<NPT * 64 / 256, 256, 0, stream>>>(
      stats + 128, g2, beta2, cnt, mmax, mmin, ovf_cnt, ovf, nbr,
      ys, zs, W2, b2, outp);
}

// Round 15
// 215.259 us; speedup vs baseline: 1.1818x; 1.0753x over previous
//
#include <hip/hip_runtime.h>

constexpr int BATCH = 8;
constexpr int PPC   = 2048;            // points per cloud
constexpr int NPT   = BATCH * PPC;     // 16384 points
constexpr int OCH   = 64;              // out channels (= in channels)
constexpr int KNN_K = 20;
constexpr int NEDGE = NPT * KNN_K;     // 327680 edges
constexpr int REVCAP = 128;            // per-row reverse-adjacency capacity
constexpr int OVCAP  = 8192;           // overflow list capacity
constexpr int QCAP   = 48;             // per-point qualifier capacity

typedef short short8 __attribute__((ext_vector_type(8)));
typedef float float4v __attribute__((ext_vector_type(4)));

// XCD-aware swizzle: blocks of one cloud all land on one XCD
__device__ __forceinline__ int xcd_swizzle(int b, int nper) {
  return (b & 7) * nper + (b >> 3);
}

__device__ __forceinline__ unsigned short bfr(float f) {  // f32 -> bf16 RNE
  unsigned u = __float_as_uint(f);
  return (unsigned short)((u + 0x7FFFu + ((u >> 16) & 1u)) >> 16);
}
__device__ __forceinline__ short8 pack8(float4 a, float4 b) {
  short8 r;
  r[0] = (short)bfr(a.x); r[1] = (short)bfr(a.y);
  r[2] = (short)bfr(a.z); r[3] = (short)bfr(a.w);
  r[4] = (short)bfr(b.x); r[5] = (short)bfr(b.y);
  r[6] = (short)bfr(b.z); r[7] = (short)bfr(b.w);
  return r;
}
__device__ __forceinline__ unsigned umed3(unsigned a, unsigned b, unsigned c) {
  unsigned d;
  asm("v_med3_u32 %0, %1, %2, %3" : "=v"(d) : "v"(a), "v"(b), "v"(c));
  return d;
}

// ---------------------------------------------------------------- kNN ------
// P1/merge/P2 use the monotone PROXY distance (4 fma, positive, u32-ordered):
//   proxy = 1000 + |p_j|^2/2 - p_i.p_j   (= 1000 + (d2 - |p_i|^2)/2)
// Threshold T' = 20th-smallest of the 48 lane-top-3 proxies; P2 pushes
// proxy <= T'+16ulp (margin >> proxy rounding skew -> superset of exact
// top-20). P3 ranks by the EXACT original d2 formula + index (unchanged).
__global__ __launch_bounds__(256) void knn_kernel(const float* __restrict__ pos,
                                                  int* __restrict__ nbr,
                                                  int* __restrict__ cnt,
                                                  int* __restrict__ ovf_cnt,
                                                  int* __restrict__ ovf,
                                                  int* __restrict__ rev) {
  __shared__ float4 cps[8 * 257];                 // region r at r*257 (+pad)
  __shared__ unsigned long long qk[16][QCAP];     // per-point qualifiers
  __shared__ int qn[16];
  const int t  = threadIdx.x;
  const int pl = t >> 4;                     // point-local 0..15
  const int s  = t & 15;                     // split 0..15
  const int lane = t & 63;
  const int eb = xcd_swizzle(blockIdx.x, NPT / 16 / 8);
  const int i  = eb * 16 + pl;
  const int cbase = i & ~(PPC - 1);

  for (int u = t; u < PPC; u += 256) {
    int j = cbase + u;
    float ax = pos[3 * j], ay = pos[3 * j + 1], az = pos[3 * j + 2];
    cps[(u >> 8) * 257 + (u & 255)] = make_float4(ax, ay, az, ax * ax + ay * ay + az * az);
  }
  if (t < 16) qn[t] = 0;
  __syncthreads();

  const int il = i - cbase;
  const float4 me = cps[(il >> 8) * 257 + (il & 255)];
  const float px = me.x, py = me.y, pz = me.z, sqi = me.w;
  const int jbase = s * 128;
  const float4* __restrict__ cp = &cps[(s >> 1) * 257 + (s & 1) * 128];

  // ---- pass 1: per-lane top-3 proxies ----
  unsigned kd[3];
  kd[0] = kd[1] = kd[2] = 0xFFFFFFFFu;
  for (int u = 0; u < 128; ++u) {
    float4 c = cp[u];
    float pr = fmaf(-px, c.x, fmaf(-py, c.y, fmaf(-pz, c.z, fmaf(0.5f, c.w, 1000.f))));
    unsigned ck = __float_as_uint(pr);
    ck = (jbase + u == il) ? 0xFFFFFFFFu : ck;
    kd[2] = umed3(kd[1], kd[2], ck);
    kd[1] = umed3(kd[0], kd[1], ck);
    kd[0] = kd[0] < ck ? kd[0] : ck;
  }

  // ---- merge: 20th smallest of the 48 proxy heads -> T ----
  unsigned T = 0xFFFFFFFFu;
  int cum = 0;
  const int grp = lane & 48;
#pragma unroll
  for (int r = 0; r < KNN_K; ++r) {
    unsigned w = kd[0];
#pragma unroll
    for (int m = 1; m < 16; m <<= 1) {
      unsigned o = (unsigned)__shfl_xor((int)w, m, 16);
      w = o < w ? o : w;
    }
    bool pop = (kd[0] == w);
    unsigned long long bal = __ballot(pop);
    int mcount = __popc((int)((bal >> grp) & 0xFFFFull));
    if (cum < KNN_K) T = w;
    cum += mcount;
    if (pop) { kd[0] = kd[1]; kd[1] = kd[2]; kd[2] = 0xFFFFFFFFu; }
  }
  const unsigned Tq = T + 16;   // +16 ulp safety margin

  // ---- pass 2: push qualifiers with EXACT d2 key ----
  for (int u = 0; u < 128; ++u) {
    float4 c = cp[u];
    float pr = fmaf(-px, c.x, fmaf(-py, c.y, fmaf(-pz, c.z, fmaf(0.5f, c.w, 1000.f))));
    unsigned ck = __float_as_uint(pr);
    ck = (jbase + u == il) ? 0xFFFFFFFFu : ck;
    if (ck <= Tq) {
      float d2 = sqi + c.w - 2.0f * (px * c.x + py * c.y + pz * c.z);
      d2 = d2 > 0.f ? d2 : 0.f;
      int slot = atomicAdd(&qn[pl], 1);
      if (slot < QCAP)
        qk[pl][slot] = ((unsigned long long)__float_as_uint(d2) << 32) | (unsigned)(jbase + u);
    }
  }
  __syncthreads();

  // ---- pass 3: exact rank + emit nbr/rev (unchanged) ----
  int n = qn[pl]; n = n < QCAP ? n : QCAP;
  for (int base = 0; base < n; base += 16) {
    int e = base + s;
    if (e < n) {
      unsigned long long mk = qk[pl][e];
      int rank = 0;
      for (int o = 0; o < n; ++o) rank += (qk[pl][o] < mk) ? 1 : 0;
      if (rank < KNN_K) {
        int j = cbase + (int)(mk & 0xFFFFFFFFull);
        int eid = i * KNN_K + rank;
        nbr[eid] = j;
        int slot = atomicAdd(&cnt[j], 1);
        if (slot < REVCAP) rev[j * REVCAP + slot] = i;   // center index
        else { int ov = atomicAdd(ovf_cnt, 1); if (ov < OVCAP) ovf[ov] = eid; }
      }
    }
  }
}

// ------------------------- node-level layer-1 GEMM (16 nodes/block) --------
__global__ __launch_bounds__(256) void node_gemm(const float* __restrict__ x,
                                                 const float* __restrict__ W1,
                                                 float* __restrict__ yv,
                                                 float* __restrict__ zv) {
  __shared__ float wa[64][65];
  __shared__ float wb[64][65];
  __shared__ float xs[16][64];
  const int t = threadIdx.x;
  for (int m = t; m < 8192; m += 256) {
    int o = m >> 7, c2 = m & 127;
    float w = W1[m];
    if (c2 < 64) wa[c2][o] = w; else wb[c2 - 64][o] = w;
  }
  for (int m = t; m < 1024; m += 256)
    xs[m >> 6][m & 63] = x[(size_t)blockIdx.x * 1024 + m];
  __syncthreads();
  const int g = t >> 6, o = t & 63;   // wave g handles nodes g*4..g*4+3
  float accA[4] = {0, 0, 0, 0}, accB[4] = {0, 0, 0, 0};
#pragma unroll 4
  for (int c = 0; c < 64; ++c) {
    float w_a = wa[c][o], w_b = wb[c][o];
#pragma unroll
    for (int q = 0; q < 4; ++q) {
      float xv = xs[g * 4 + q][c];
      accA[q] = fmaf(xv, w_a, accA[q]);
      accB[q] = fmaf(xv, w_b, accB[q]);
    }
  }
#pragma unroll
  for (int q = 0; q < 4; ++q) {
    size_t n = (size_t)blockIdx.x * 16 + g * 4 + q;
    yv[n * 64 + o] = accA[q] - accB[q];
    zv[n * 64 + o] = accB[q];
  }
}

// ---------------------------- BN1 stats: center-grouped (z once, 20 y rows) -
__global__ __launch_bounds__(256) void bn1_stats(const int* __restrict__ nbr,
                                                 const float4* __restrict__ yv4,
                                                 const float4* __restrict__ zv4,
                                                 const float* __restrict__ b1,
                                                 float* __restrict__ stats) {
  const int t  = threadIdx.x;
  const int c4 = t & 15;
  const int lane = t & 63;
  const int eb = xcd_swizzle(blockIdx.x, NPT / 16 / 8);
  const int i  = eb * 16 + (t >> 4);
  const float4 bo = reinterpret_cast<const float4*>(b1)[c4];
  float4 z = zv4[(size_t)i * 16 + c4];
  float4 zb = make_float4(z.x + bo.x, z.y + bo.y, z.z + bo.z, z.w + bo.w);
  int jA = nbr[i * KNN_K + c4];
  int jB = nbr[i * KNN_K + 16 + (c4 & 3)];
  float4 s1 = make_float4(0, 0, 0, 0), s2 = make_float4(0, 0, 0, 0);
#pragma unroll
  for (int q = 0; q < 16; ++q) {
    int j = __shfl(jA, (lane & 48) + q);
    float4 y = yv4[(size_t)j * 16 + c4];
    float sx = y.x + zb.x, sy = y.y + zb.y, sz = y.z + zb.z, sw = y.w + zb.w;
    s1.x += sx; s1.y += sy; s1.z += sz; s1.w += sw;
    s2.x += sx * sx; s2.y += sy * sy; s2.z += sz * sz; s2.w += sw * sw;
  }
#pragma unroll
  for (int q = 0; q < 4; ++q) {
    int j = __shfl(jB, (lane & 48) + q);
    float4 y = yv4[(size_t)j * 16 + c4];
    float sx = y.x + zb.x, sy = y.y + zb.y, sz = y.z + zb.z, sw = y.w + zb.w;
    s1.x += sx; s1.y += sy; s1.z += sz; s1.w += sw;
    s2.x += sx * sx; s2.y += sy * sy; s2.z += sz * sz; s2.w += sw * sw;
  }
  s1.x += __shfl_xor(s1.x, 16); s1.y += __shfl_xor(s1.y, 16);
  s1.z += __shfl_xor(s1.z, 16); s1.w += __shfl_xor(s1.w, 16);
  s2.x += __shfl_xor(s2.x, 16); s2.y += __shfl_xor(s2.y, 16);
  s2.z += __shfl_xor(s2.z, 16); s2.w += __shfl_xor(s2.w, 16);
  s1.x += __shfl_xor(s1.x, 32); s1.y += __shfl_xor(s1.y, 32);
  s1.z += __shfl_xor(s1.z, 32); s1.w += __shfl_xor(s1.w, 32);
  s2.x += __shfl_xor(s2.x, 32); s2.y += __shfl_xor(s2.y, 32);
  s2.z += __shfl_xor(s2.z, 32); s2.w += __shfl_xor(s2.w, 32);
  __shared__ float ss[2][64];
  if (t < 128) { ss[0][t & 63] = 0.f; }
  __syncthreads();
  if ((t & 48) == 0) {
    atomicAdd(&ss[0][c4 * 4 + 0], s1.x); atomicAdd(&ss[0][c4 * 4 + 1], s1.y);
    atomicAdd(&ss[0][c4 * 4 + 2], s1.z); atomicAdd(&ss[0][c4 * 4 + 3], s1.w);
    atomicAdd(&ss[1][c4 * 4 + 0], s2.x); atomicAdd(&ss[1][c4 * 4 + 1], s2.y);
    atomicAdd(&ss[1][c4 * 4 + 2], s2.z); atomicAdd(&ss[1][c4 * 4 + 3], s2.w);
  }
  __syncthreads();
  if (t < 64)       atomicAdd(&stats[t], ss[0][t]);
  else if (t < 128) atomicAdd(&stats[64 + (t - 64)], ss[1][t - 64]);
}

// ------------- pre-apply BN1: Ys = y*a1 ; Zs = z*a1 + (b1*a1 + c1) ---------
__global__ __launch_bounds__(256) void scale_yz(
    const float4* __restrict__ yv4, const float4* __restrict__ zv4,
    const float* __restrict__ stats1, const float* __restrict__ g1,
    const float* __restrict__ beta1, const float* __restrict__ b1,
    float4* __restrict__ ys4, float4* __restrict__ zs4) {
  const int idx = blockIdx.x * 256 + threadIdx.x;   // over NPT*16
  const int c4 = idx & 15;
  constexpr float invE = 1.0f / NEDGE;
  float a[4], c[4];
#pragma unroll
  for (int q = 0; q < 4; ++q) {
    int ch = c4 * 4 + q;
    float mu  = stats1[ch] * invE;
    float var = stats1[64 + ch] * invE - mu * mu;
    float av  = g1[ch] * rsqrtf(var + 1e-5f);
    a[q] = av;
    c[q] = fmaf(b1[ch], av, beta1[ch] - mu * av);
  }
  float4 y = yv4[idx];
  float4 z = zv4[idx];
  ys4[idx] = make_float4(y.x * a[0], y.y * a[1], y.z * a[2], y.w * a[3]);
  zs4[idx] = make_float4(fmaf(z.x, a[0], c[0]), fmaf(z.y, a[1], c[1]),
                         fmaf(z.z, a[2], c[2]), fmaf(z.w, a[3], c[3]));
}

// ----------- per-wave row-owned GEMM2 (bf16 MFMA), row-pipelined -----------
// Wave owns 4 consecutive rows; next row's rev/ys loads issued before the
// current row's tiles (overlaps the serial cnt->rev->shfl->gather chain).
__global__ __launch_bounds__(256) void gemm2_row(
    const float4* __restrict__ ys4, const float4* __restrict__ zs4,
    const float* __restrict__ W2, const float* __restrict__ b2,
    const int* __restrict__ cnt, const int* __restrict__ rev,
    float* __restrict__ stats2, float* __restrict__ mmax,
    float* __restrict__ mmin) {
  __shared__ float ss[2][64];
  const int t = threadIdx.x, lane = t & 63;
  const int col = lane & 15, quad = lane >> 4;
  const int eb = xcd_swizzle(blockIdx.x, NPT / 16 / 8);
  const int wid = eb * 4 + (t >> 6);

  // W2 B-fragments into registers
  short8 bf0[4], bf1[4];
  const float4* __restrict__ W2v = (const float4*)W2;
#pragma unroll
  for (int nt = 0; nt < 4; ++nt) {
    int row = nt * 16 + col;
    float4 wa = W2v[row * 16 + quad * 2];
    float4 wb = W2v[row * 16 + quad * 2 + 1];
    float4 wc = W2v[row * 16 + 8 + quad * 2];
    float4 wd = W2v[row * 16 + 8 + quad * 2 + 1];
    bf0[nt] = pack8(wa, wb);
    bf1[nt] = pack8(wc, wd);
  }
  float b2r[4];
#pragma unroll
  for (int nt = 0; nt < 4; ++nt) b2r[nt] = b2[nt * 16 + col];

  // all 4 row counts at once
  int4 cq = *reinterpret_cast<const int4*>(&cnt[wid * 4]);
  int nA[4] = {cq.x, cq.y, cq.z, cq.w};
#pragma unroll
  for (int q = 0; q < 4; ++q) nA[q] = nA[q] < REVCAP ? nA[q] : REVCAP;

  float s1[4] = {0, 0, 0, 0}, s2[4] = {0, 0, 0, 0};
  // prefetch row 0 (unconditional loads; garbage beyond n is clamped later)
  int rv0 = rev[(size_t)(wid * 4) * REVCAP + lane];
  int rv1 = rev[(size_t)(wid * 4) * REVCAP + 64 + lane];
  float4 ya = ys4[(size_t)(wid * 4) * 16 + quad * 2];
  float4 yb = ys4[(size_t)(wid * 4) * 16 + quad * 2 + 1];
  float4 yc = ys4[(size_t)(wid * 4) * 16 + 8 + quad * 2];
  float4 yd = ys4[(size_t)(wid * 4) * 16 + 8 + quad * 2 + 1];

#pragma unroll
  for (int rr = 0; rr < 4; ++rr) {
    const int row = wid * 4 + rr;
    const int n = nA[rr];
    // issue next row's loads before this row's dependent work
    int nrv0 = 0, nrv1 = 0;
    float4 nya, nyb, nyc, nyd;
    if (rr < 3) {
      const int nrow = row + 1;
      nrv0 = rev[(size_t)nrow * REVCAP + lane];
      nrv1 = rev[(size_t)nrow * REVCAP + 64 + lane];
      nya = ys4[(size_t)nrow * 16 + quad * 2];
      nyb = ys4[(size_t)nrow * 16 + quad * 2 + 1];
      nyc = ys4[(size_t)nrow * 16 + 8 + quad * 2];
      nyd = ys4[(size_t)nrow * 16 + 8 + quad * 2 + 1];
    }
    float mx[4], mn[4];
#pragma unroll
    for (int nt = 0; nt < 4; ++nt) { mx[nt] = -1e30f; mn[nt] = 1e30f; }

    auto tile_body = [&](int tbase, float4 za, float4 zb, float4 zc, float4 zd) {
      float h[16];
      h[0]  = ya.x + za.x; h[1]  = ya.y + za.y; h[2]  = ya.z + za.z; h[3]  = ya.w + za.w;
      h[4]  = yb.x + zb.x; h[5]  = yb.y + zb.y; h[6]  = yb.z + zb.z; h[7]  = yb.w + zb.w;
      h[8]  = yc.x + zc.x; h[9]  = yc.y + zc.y; h[10] = yc.z + zc.z; h[11] = yc.w + zc.w;
      h[12] = yd.x + zd.x; h[13] = yd.y + zd.y; h[14] = yd.z + zd.z; h[15] = yd.w + zd.w;
      short8 af0, af1;
#pragma unroll
      for (int q = 0; q < 8; ++q) {
        float u0 = h[q]     > 0.f ? h[q]     : 0.f;
        float u1 = h[8 + q] > 0.f ? h[8 + q] : 0.f;
        af0[q] = (short)bfr(u0);
        af1[q] = (short)bfr(u1);
      }
      float4v acc[4];
#pragma unroll
      for (int nt = 0; nt < 4; ++nt) {
        acc[nt] = (float4v){0.f, 0.f, 0.f, 0.f};
        acc[nt] = __builtin_amdgcn_mfma_f32_16x16x32_bf16(af0, bf0[nt], acc[nt], 0, 0, 0);
        acc[nt] = __builtin_amdgcn_mfma_f32_16x16x32_bf16(af1, bf1[nt], acc[nt], 0, 0, 0);
      }
#pragma unroll
      for (int r = 0; r < 4; ++r) {
        bool v = (tbase + quad * 4 + r) < n;
#pragma unroll
        for (int nt = 0; nt < 4; ++nt) {
          float val = acc[nt][r] + b2r[nt];
          if (v) {
            s1[nt] += val; s2[nt] += val * val;
            mx[nt] = val > mx[nt] ? val : mx[nt];
            mn[nt] = val < mn[nt] ? val : mn[nt];
          }
        }
      }
    };

    int icA = __shfl(rv0, col);       icA = (col < n) ? icA : 0;
    int icB = __shfl(rv0, 16 + col);  icB = (16 + col < n) ? icB : 0;
    float4 zAa = zs4[(size_t)icA * 16 + quad * 2];
    float4 zAb = zs4[(size_t)icA * 16 + quad * 2 + 1];
    float4 zAc = zs4[(size_t)icA * 16 + 8 + quad * 2];
    float4 zAd = zs4[(size_t)icA * 16 + 8 + quad * 2 + 1];
    float4 zBa = zs4[(size_t)icB * 16 + quad * 2];
    float4 zBb = zs4[(size_t)icB * 16 + quad * 2 + 1];
    float4 zBc = zs4[(size_t)icB * 16 + 8 + quad * 2];
    float4 zBd = zs4[(size_t)icB * 16 + 8 + quad * 2 + 1];
    tile_body(0, zAa, zAb, zAc, zAd);
    if (n > 16) tile_body(16, zBa, zBb, zBc, zBd);
    for (int ti = 2; ti * 16 < n; ++ti) {
      int gi = ti * 16 + col;
      int v0 = __shfl(rv0, gi & 63);
      int v1 = __shfl(rv1, gi & 63);
      int ic = (gi < 64) ? v0 : v1;
      ic = (gi < n) ? ic : 0;
      float4 za = zs4[(size_t)ic * 16 + quad * 2];
      float4 zb = zs4[(size_t)ic * 16 + quad * 2 + 1];
      float4 zc = zs4[(size_t)ic * 16 + 8 + quad * 2];
      float4 zd = zs4[(size_t)ic * 16 + 8 + quad * 2 + 1];
      tile_body(ti * 16, za, zb, zc, zd);
    }
#pragma unroll
    for (int nt = 0; nt < 4; ++nt) {
      mx[nt] = fmaxf(mx[nt], __shfl_xor(mx[nt], 16));
      mx[nt] = fmaxf(mx[nt], __shfl_xor(mx[nt], 32));
      mn[nt] = fminf(mn[nt], __shfl_xor(mn[nt], 16));
      mn[nt] = fminf(mn[nt], __shfl_xor(mn[nt], 32));
    }
    if (quad == 0) {
#pragma unroll
      for (int nt = 0; nt < 4; ++nt) {
        mmax[(size_t)row * 64 + nt * 16 + col] = mx[nt];
        mmin[(size_t)row * 64 + nt * 16 + col] = mn[nt];
      }
    }
    rv0 = nrv0; rv1 = nrv1;
    ya = nya; yb = nyb; yc = nyc; yd = nyd;
  }
  // block-level stats reduction
  if (t < 128) ss[t >> 6][t & 63] = 0.f;
  __syncthreads();
#pragma unroll
  for (int nt = 0; nt < 4; ++nt) {
    s1[nt] += __shfl_xor(s1[nt], 16);
    s1[nt] += __shfl_xor(s1[nt], 32);
    s2[nt] += __shfl_xor(s2[nt], 16);
    s2[nt] += __shfl_xor(s2[nt], 32);
  }
  if (quad == 0) {
#pragma unroll
    for (int nt = 0; nt < 4; ++nt) {
      atomicAdd(&ss[0][nt * 16 + col], s1[nt]);
      atomicAdd(&ss[1][nt * 16 + col], s2[nt]);
    }
  }
  __syncthreads();
  if (t < 64)       atomicAdd(&stats2[t], ss[0][t]);
  else if (t < 128) atomicAdd(&stats2[64 + (t - 64)], ss[1][t - 64]);
}

// ---------------- finalize: BN2 affine of per-row max/min + relu + empties -
__global__ __launch_bounds__(256) void finalize_out(
    const float* __restrict__ stats2, const float* __restrict__ g2,
    const float* __restrict__ beta2, const int* __restrict__ cnt,
    const float* __restrict__ mmax, const float* __restrict__ mmin,
    const int* __restrict__ ovf_cnt, const int* __restrict__ ovf,
    const int* __restrict__ nbr, const float* __restrict__ ys,
    const float* __restrict__ zs, const float* __restrict__ W2,
    const float* __restrict__ b2, float* __restrict__ outp) {
  const int idx = blockIdx.x * 256 + threadIdx.x;
  const int row = idx >> 6, ch = idx & 63;
  constexpr float invE = 1.0f / NEDGE;
  float mu  = stats2[ch] * invE;
  float var = stats2[64 + ch] * invE - mu * mu;
  float a2  = g2[ch] * rsqrtf(var + 1e-5f);
  float c2  = beta2[ch] - mu * a2;
  float h = (a2 >= 0.f) ? mmax[idx] : mmin[idx];
  int ov = ovf_cnt[0]; ov = ov > OVCAP ? OVCAP : ov;
  for (int u = 0; u < ov; ++u) {
    int e = ovf[u];
    if (nbr[e] == row) {
      int ic = e / KNN_K;
      float accv = 0.f;
      for (int k = 0; k < 64; ++k) {
        float hh = ys[(size_t)row * 64 + k] + zs[(size_t)ic * 64 + k];
        hh = hh > 0.f ? hh : 0.f;
        accv = fmaf(hh, W2[ch * 64 + k], accv);
      }
      float v = accv + b2[ch];
      if (a2 >= 0.f) h = v > h ? v : h; else h = v < h ? v : h;
    }
  }
  float o = (cnt[row] > 0) ? fmaf(h, a2, c2) : 0.0f;
  outp[idx] = o > 0.f ? o : 0.f;
}

// --------------------------------------------------------------- launch ----
extern "C" void kernel_launch(void* const* d_in, const int* in_sizes, int n_in,
                              void* d_out, int out_size, void* d_ws, size_t ws_size,
                              hipStream_t stream) {
  (void)in_sizes; (void)n_in; (void)out_size; (void)ws_size;
  const float* x     = (const float*)d_in[0];
  const float* pos   = (const float*)d_in[1];
  const float* W1    = (const float*)d_in[3];
  const float* b1    = (const float*)d_in[4];
  const float* g1    = (const float*)d_in[5];
  const float* beta1 = (const float*)d_in[6];
  const float* W2    = (const float*)d_in[7];
  const float* b2    = (const float*)d_in[8];
  const float* g2    = (const float*)d_in[9];
  const float* beta2 = (const float*)d_in[10];
  float* outp = (float*)d_out;

  char* w = (char*)d_ws;
  int*   nbr     = (int*)w;                            // 1,310,720 B
  float* yv      = (float*)(w + 1310720);              // 4,194,304 B
  float* zv      = (float*)(w + 5505024);              // 4,194,304 B
  float* stats   = (float*)(w + 9699328);              // 1,024 B
  int*   cnt     = (int*)(w + 9700352);                // 65,536 B
  int*   ovf_cnt = (int*)(w + 9765888);                // 64 B
  int*   ovf     = (int*)(w + 9765952);                // 32,768 B
  int*   rev     = (int*)(w + 9798720);                // 8,388,608 B -> 18,187,328
  float* mmax    = (float*)(w + 18187328);             // 4,194,304 B
  float* mmin    = (float*)(w + 22381632);             // 4,194,304 B -> 26,575,936
  float* ys      = (float*)(w + 26575936);             // 4,194,304 B
  float* zs      = (float*)(w + 30770240);             // 4,194,304 B -> 34,964,544

  hipMemsetAsync(stats, 0, 1024, stream);
  hipMemsetAsync(cnt, 0, 65536 + 64, stream);

  knn_kernel<<<NPT / 16, 256, 0, stream>>>(pos, nbr, cnt, ovf_cnt, ovf, rev);
  node_gemm<<<NPT / 16, 256, 0, stream>>>(x, W1, yv, zv);
  bn1_stats<<<NPT / 16, 256, 0, stream>>>(nbr, (const float4*)yv, (const float4*)zv, b1, stats);
  scale_yz<<<NPT * 16 / 256, 256, 0, stream>>>(
      (const float4*)yv, (const float4*)zv, stats, g1, beta1, b1,
      (float4*)ys, (float4*)zs);
  gemm2_row<<<NPT / 16, 256, 0, stream>>>(
      (const float4*)ys, (const float4*)zs, W2, b2,
      cnt, rev, stats + 128, mmax, mmin);
  finalize_out<<<NPT * 64 / 256, 256, 0, stream>>>(
      stats + 128, g2, beta2, cnt, mmax, mmin, ovf_cnt, ovf, nbr,
      ys, zs, W2, b2, outp);
}

// Round 16
// 188.089 us; speedup vs baseline: 1.3525x; 1.1445x over previous
//
#include <hip/hip_runtime.h>

constexpr int BATCH = 8;
constexpr int PPC   = 2048;            // points per cloud
constexpr int NPT   = BATCH * PPC;     // 16384 points
constexpr int OCH   = 64;              // out channels (= in channels)
constexpr int KNN_K = 20;
constexpr int NEDGE = NPT * KNN_K;     // 327680 edges
constexpr int REVCAP = 128;            // per-row reverse-adjacency capacity
constexpr int OVCAP  = 8192;           // overflow list capacity
constexpr int QCAP   = 48;             // per-point qualifier capacity
constexpr int NPART  = 32;             // stat partial buffers (de-contended atomics)

typedef short short8 __attribute__((ext_vector_type(8)));
typedef float float4v __attribute__((ext_vector_type(4)));

// XCD-aware swizzle: blocks of one cloud all land on one XCD
__device__ __forceinline__ int xcd_swizzle(int b, int nper) {
  return (b & 7) * nper + (b >> 3);
}

__device__ __forceinline__ unsigned short bfr(float f) {  // f32 -> bf16 RNE
  unsigned u = __float_as_uint(f);
  return (unsigned short)((u + 0x7FFFu + ((u >> 16) & 1u)) >> 16);
}
__device__ __forceinline__ short8 pack8(float4 a, float4 b) {
  short8 r;
  r[0] = (short)bfr(a.x); r[1] = (short)bfr(a.y);
  r[2] = (short)bfr(a.z); r[3] = (short)bfr(a.w);
  r[4] = (short)bfr(b.x); r[5] = (short)bfr(b.y);
  r[6] = (short)bfr(b.z); r[7] = (short)bfr(b.w);
  return r;
}
__device__ __forceinline__ unsigned umed3(unsigned a, unsigned b, unsigned c) {
  unsigned d;
  asm("v_med3_u32 %0, %1, %2, %3" : "=v"(d) : "v"(a), "v"(b), "v"(c));
  return d;
}

// ---------------------------------------------------------------- kNN ------
__global__ __launch_bounds__(256) void knn_kernel(const float* __restrict__ pos,
                                                  int* __restrict__ nbr,
                                                  int* __restrict__ cnt,
                                                  int* __restrict__ ovf_cnt,
                                                  int* __restrict__ ovf,
                                                  int* __restrict__ rev) {
  __shared__ float4 cps[8 * 257];                 // region r at r*257 (+pad)
  __shared__ unsigned long long qk[16][QCAP];     // per-point qualifiers
  __shared__ int qn[16];
  const int t  = threadIdx.x;
  const int pl = t >> 4;                     // point-local 0..15
  const int s  = t & 15;                     // split 0..15
  const int lane = t & 63;
  const int eb = xcd_swizzle(blockIdx.x, NPT / 16 / 8);
  const int i  = eb * 16 + pl;
  const int cbase = i & ~(PPC - 1);

  for (int u = t; u < PPC; u += 256) {
    int j = cbase + u;
    float ax = pos[3 * j], ay = pos[3 * j + 1], az = pos[3 * j + 2];
    cps[(u >> 8) * 257 + (u & 255)] = make_float4(ax, ay, az, ax * ax + ay * ay + az * az);
  }
  if (t < 16) qn[t] = 0;
  __syncthreads();

  const int il = i - cbase;
  const float4 me = cps[(il >> 8) * 257 + (il & 255)];
  const float px = me.x, py = me.y, pz = me.z, sqi = me.w;
  const int jbase = s * 128;
  const float4* __restrict__ cp = &cps[(s >> 1) * 257 + (s & 1) * 128];

  // ---- pass 1: per-lane top-3 proxies (proxy monotone in d2) ----
  unsigned kd[3];
  kd[0] = kd[1] = kd[2] = 0xFFFFFFFFu;
  for (int u = 0; u < 128; ++u) {
    float4 c = cp[u];
    float pr = fmaf(-px, c.x, fmaf(-py, c.y, fmaf(-pz, c.z, fmaf(0.5f, c.w, 1000.f))));
    unsigned ck = __float_as_uint(pr);
    ck = (jbase + u == il) ? 0xFFFFFFFFu : ck;
    kd[2] = umed3(kd[1], kd[2], ck);
    kd[1] = umed3(kd[0], kd[1], ck);
    kd[0] = kd[0] < ck ? kd[0] : ck;
  }

  // ---- merge: 20th smallest of the 48 proxy heads -> T ----
  unsigned T = 0xFFFFFFFFu;
  int cum = 0;
  const int grp = lane & 48;
#pragma unroll
  for (int r = 0; r < KNN_K; ++r) {
    unsigned w = kd[0];
#pragma unroll
    for (int m = 1; m < 16; m <<= 1) {
      unsigned o = (unsigned)__shfl_xor((int)w, m, 16);
      w = o < w ? o : w;
    }
    bool pop = (kd[0] == w);
    unsigned long long bal = __ballot(pop);
    int mcount = __popc((int)((bal >> grp) & 0xFFFFull));
    if (cum < KNN_K) T = w;
    cum += mcount;
    if (pop) { kd[0] = kd[1]; kd[1] = kd[2]; kd[2] = 0xFFFFFFFFu; }
  }
  const unsigned Tq = T + 16;   // +16 ulp safety margin

  // ---- pass 2: push qualifiers with EXACT d2 key ----
  for (int u = 0; u < 128; ++u) {
    float4 c = cp[u];
    float pr = fmaf(-px, c.x, fmaf(-py, c.y, fmaf(-pz, c.z, fmaf(0.5f, c.w, 1000.f))));
    unsigned ck = __float_as_uint(pr);
    ck = (jbase + u == il) ? 0xFFFFFFFFu : ck;
    if (ck <= Tq) {
      float d2 = sqi + c.w - 2.0f * (px * c.x + py * c.y + pz * c.z);
      d2 = d2 > 0.f ? d2 : 0.f;
      int slot = atomicAdd(&qn[pl], 1);
      if (slot < QCAP)
        qk[pl][slot] = ((unsigned long long)__float_as_uint(d2) << 32) | (unsigned)(jbase + u);
    }
  }
  __syncthreads();

  // ---- pass 3: exact rank + emit nbr/rev ----
  int n = qn[pl]; n = n < QCAP ? n : QCAP;
  for (int base = 0; base < n; base += 16) {
    int e = base + s;
    if (e < n) {
      unsigned long long mk = qk[pl][e];
      int rank = 0;
      for (int o = 0; o < n; ++o) rank += (qk[pl][o] < mk) ? 1 : 0;
      if (rank < KNN_K) {
        int j = cbase + (int)(mk & 0xFFFFFFFFull);
        int eid = i * KNN_K + rank;
        nbr[eid] = j;
        int slot = atomicAdd(&cnt[j], 1);
        if (slot < REVCAP) rev[j * REVCAP + slot] = i;   // center index
        else { int ov = atomicAdd(ovf_cnt, 1); if (ov < OVCAP) ovf[ov] = eid; }
      }
    }
  }
}

// ------------------------- node-level layer-1 GEMM (16 nodes/block) --------
__global__ __launch_bounds__(256) void node_gemm(const float* __restrict__ x,
                                                 const float* __restrict__ W1,
                                                 float* __restrict__ yv,
                                                 float* __restrict__ zv) {
  __shared__ float wa[64][65];
  __shared__ float wb[64][65];
  __shared__ float xs[16][64];
  const int t = threadIdx.x;
  for (int m = t; m < 8192; m += 256) {
    int o = m >> 7, c2 = m & 127;
    float w = W1[m];
    if (c2 < 64) wa[c2][o] = w; else wb[c2 - 64][o] = w;
  }
  for (int m = t; m < 1024; m += 256)
    xs[m >> 6][m & 63] = x[(size_t)blockIdx.x * 1024 + m];
  __syncthreads();
  const int g = t >> 6, o = t & 63;
  float accA[4] = {0, 0, 0, 0}, accB[4] = {0, 0, 0, 0};
#pragma unroll 4
  for (int c = 0; c < 64; ++c) {
    float w_a = wa[c][o], w_b = wb[c][o];
#pragma unroll
    for (int q = 0; q < 4; ++q) {
      float xv = xs[g * 4 + q][c];
      accA[q] = fmaf(xv, w_a, accA[q]);
      accB[q] = fmaf(xv, w_b, accB[q]);
    }
  }
#pragma unroll
  for (int q = 0; q < 4; ++q) {
    size_t n = (size_t)blockIdx.x * 16 + g * 4 + q;
    yv[n * 64 + o] = accA[q] - accB[q];
    zv[n * 64 + o] = accB[q];
  }
}

// ---------------------------- BN1 stats -> 32-way partial buffers ----------
__global__ __launch_bounds__(256) void bn1_stats(const int* __restrict__ nbr,
                                                 const float4* __restrict__ yv4,
                                                 const float4* __restrict__ zv4,
                                                 const float* __restrict__ b1,
                                                 float* __restrict__ bn1p) {
  const int t  = threadIdx.x;
  const int c4 = t & 15;
  const int lane = t & 63;
  const int eb = xcd_swizzle(blockIdx.x, NPT / 16 / 8);
  const int i  = eb * 16 + (t >> 4);
  const float4 bo = reinterpret_cast<const float4*>(b1)[c4];
  float4 z = zv4[(size_t)i * 16 + c4];
  float4 zb = make_float4(z.x + bo.x, z.y + bo.y, z.z + bo.z, z.w + bo.w);
  int jA = nbr[i * KNN_K + c4];
  int jB = nbr[i * KNN_K + 16 + (c4 & 3)];
  float4 s1 = make_float4(0, 0, 0, 0), s2 = make_float4(0, 0, 0, 0);
#pragma unroll
  for (int q = 0; q < 16; ++q) {
    int j = __shfl(jA, (lane & 48) + q);
    float4 y = yv4[(size_t)j * 16 + c4];
    float sx = y.x + zb.x, sy = y.y + zb.y, sz = y.z + zb.z, sw = y.w + zb.w;
    s1.x += sx; s1.y += sy; s1.z += sz; s1.w += sw;
    s2.x += sx * sx; s2.y += sy * sy; s2.z += sz * sz; s2.w += sw * sw;
  }
#pragma unroll
  for (int q = 0; q < 4; ++q) {
    int j = __shfl(jB, (lane & 48) + q);
    float4 y = yv4[(size_t)j * 16 + c4];
    float sx = y.x + zb.x, sy = y.y + zb.y, sz = y.z + zb.z, sw = y.w + zb.w;
    s1.x += sx; s1.y += sy; s1.z += sz; s1.w += sw;
    s2.x += sx * sx; s2.y += sy * sy; s2.z += sz * sz; s2.w += sw * sw;
  }
  s1.x += __shfl_xor(s1.x, 16); s1.y += __shfl_xor(s1.y, 16);
  s1.z += __shfl_xor(s1.z, 16); s1.w += __shfl_xor(s1.w, 16);
  s2.x += __shfl_xor(s2.x, 16); s2.y += __shfl_xor(s2.y, 16);
  s2.z += __shfl_xor(s2.z, 16); s2.w += __shfl_xor(s2.w, 16);
  s1.x += __shfl_xor(s1.x, 32); s1.y += __shfl_xor(s1.y, 32);
  s1.z += __shfl_xor(s1.z, 32); s1.w += __shfl_xor(s1.w, 32);
  s2.x += __shfl_xor(s2.x, 32); s2.y += __shfl_xor(s2.y, 32);
  s2.z += __shfl_xor(s2.z, 32); s2.w += __shfl_xor(s2.w, 32);
  __shared__ float ss[2][64];
  if (t < 128) { ss[0][t & 63] = 0.f; }
  __syncthreads();
  if ((t & 48) == 0) {
    atomicAdd(&ss[0][c4 * 4 + 0], s1.x); atomicAdd(&ss[0][c4 * 4 + 1], s1.y);
    atomicAdd(&ss[0][c4 * 4 + 2], s1.z); atomicAdd(&ss[0][c4 * 4 + 3], s1.w);
    atomicAdd(&ss[1][c4 * 4 + 0], s2.x); atomicAdd(&ss[1][c4 * 4 + 1], s2.y);
    atomicAdd(&ss[1][c4 * 4 + 2], s2.z); atomicAdd(&ss[1][c4 * 4 + 3], s2.w);
  }
  __syncthreads();
  const int pb = (blockIdx.x & (NPART - 1)) * 128;
  if (t < 64)       atomicAdd(&bn1p[pb + t], ss[0][t]);
  else if (t < 128) atomicAdd(&bn1p[pb + 64 + (t - 64)], ss[1][t - 64]);
}

// ------------- pre-apply BN1 (sums 32 partials block-locally) --------------
__global__ __launch_bounds__(256) void scale_yz(
    const float4* __restrict__ yv4, const float4* __restrict__ zv4,
    const float* __restrict__ bn1p, const float* __restrict__ g1,
    const float* __restrict__ beta1, const float* __restrict__ b1,
    float4* __restrict__ ys4, float4* __restrict__ zs4) {
  __shared__ float red[128];
  const int t = threadIdx.x;
  if (t < 128) {
    float v = 0.f;
#pragma unroll
    for (int k = 0; k < NPART; ++k) v += bn1p[k * 128 + t];
    red[t] = v;
  }
  __syncthreads();
  const int idx = blockIdx.x * 256 + t;   // over NPT*16
  const int c4 = idx & 15;
  constexpr float invE = 1.0f / NEDGE;
  float a[4], c[4];
#pragma unroll
  for (int q = 0; q < 4; ++q) {
    int ch = c4 * 4 + q;
    float mu  = red[ch] * invE;
    float var = red[64 + ch] * invE - mu * mu;
    float av  = g1[ch] * rsqrtf(var + 1e-5f);
    a[q] = av;
    c[q] = fmaf(b1[ch], av, beta1[ch] - mu * av);
  }
  float4 y = yv4[idx];
  float4 z = zv4[idx];
  ys4[idx] = make_float4(y.x * a[0], y.y * a[1], y.z * a[2], y.w * a[3]);
  zs4[idx] = make_float4(fmaf(z.x, a[0], c[0]), fmaf(z.y, a[1], c[1]),
                         fmaf(z.z, a[2], c[2]), fmaf(z.w, a[3], c[3]));
}

// ----------- per-wave row-owned GEMM2 (bf16 MFMA), row-pipelined -----------
__global__ __launch_bounds__(256) void gemm2_row(
    const float4* __restrict__ ys4, const float4* __restrict__ zs4,
    const float* __restrict__ W2, const float* __restrict__ b2,
    const int* __restrict__ cnt, const int* __restrict__ rev,
    float* __restrict__ bn2p, float* __restrict__ mmax,
    float* __restrict__ mmin) {
  __shared__ float ss[2][64];
  const int t = threadIdx.x, lane = t & 63;
  const int col = lane & 15, quad = lane >> 4;
  const int eb = xcd_swizzle(blockIdx.x, NPT / 16 / 8);
  const int wid = eb * 4 + (t >> 6);

  short8 bf0[4], bf1[4];
  const float4* __restrict__ W2v = (const float4*)W2;
#pragma unroll
  for (int nt = 0; nt < 4; ++nt) {
    int row = nt * 16 + col;
    float4 wa = W2v[row * 16 + quad * 2];
    float4 wb = W2v[row * 16 + quad * 2 + 1];
    float4 wc = W2v[row * 16 + 8 + quad * 2];
    float4 wd = W2v[row * 16 + 8 + quad * 2 + 1];
    bf0[nt] = pack8(wa, wb);
    bf1[nt] = pack8(wc, wd);
  }
  float b2r[4];
#pragma unroll
  for (int nt = 0; nt < 4; ++nt) b2r[nt] = b2[nt * 16 + col];

  int4 cq = *reinterpret_cast<const int4*>(&cnt[wid * 4]);
  int nA[4] = {cq.x, cq.y, cq.z, cq.w};
#pragma unroll
  for (int q = 0; q < 4; ++q) nA[q] = nA[q] < REVCAP ? nA[q] : REVCAP;

  float s1[4] = {0, 0, 0, 0}, s2[4] = {0, 0, 0, 0};
  int rv0 = rev[(size_t)(wid * 4) * REVCAP + lane];
  int rv1 = (nA[0] > 64) ? rev[(size_t)(wid * 4) * REVCAP + 64 + lane] : 0;
  float4 ya = ys4[(size_t)(wid * 4) * 16 + quad * 2];
  float4 yb = ys4[(size_t)(wid * 4) * 16 + quad * 2 + 1];
  float4 yc = ys4[(size_t)(wid * 4) * 16 + 8 + quad * 2];
  float4 yd = ys4[(size_t)(wid * 4) * 16 + 8 + quad * 2 + 1];

#pragma unroll
  for (int rr = 0; rr < 4; ++rr) {
    const int row = wid * 4 + rr;
    const int n = nA[rr];
    int nrv0 = 0, nrv1 = 0;
    float4 nya, nyb, nyc, nyd;
    if (rr < 3) {
      const int nrow = row + 1;
      nrv0 = rev[(size_t)nrow * REVCAP + lane];
      nrv1 = (nA[rr + 1] > 64) ? rev[(size_t)nrow * REVCAP + 64 + lane] : 0;
      nya = ys4[(size_t)nrow * 16 + quad * 2];
      nyb = ys4[(size_t)nrow * 16 + quad * 2 + 1];
      nyc = ys4[(size_t)nrow * 16 + 8 + quad * 2];
      nyd = ys4[(size_t)nrow * 16 + 8 + quad * 2 + 1];
    }
    float mx[4], mn[4];
#pragma unroll
    for (int nt = 0; nt < 4; ++nt) { mx[nt] = -1e30f; mn[nt] = 1e30f; }

    auto tile_body = [&](int tbase, float4 za, float4 zb, float4 zc, float4 zd) {
      float h[16];
      h[0]  = ya.x + za.x; h[1]  = ya.y + za.y; h[2]  = ya.z + za.z; h[3]  = ya.w + za.w;
      h[4]  = yb.x + zb.x; h[5]  = yb.y + zb.y; h[6]  = yb.z + zb.z; h[7]  = yb.w + zb.w;
      h[8]  = yc.x + zc.x; h[9]  = yc.y + zc.y; h[10] = yc.z + zc.z; h[11] = yc.w + zc.w;
      h[12] = yd.x + zd.x; h[13] = yd.y + zd.y; h[14] = yd.z + zd.z; h[15] = yd.w + zd.w;
      short8 af0, af1;
#pragma unroll
      for (int q = 0; q < 8; ++q) {
        float u0 = h[q]     > 0.f ? h[q]     : 0.f;
        float u1 = h[8 + q] > 0.f ? h[8 + q] : 0.f;
        af0[q] = (short)bfr(u0);
        af1[q] = (short)bfr(u1);
      }
      float4v acc[4];
#pragma unroll
      for (int nt = 0; nt < 4; ++nt) {
        acc[nt] = (float4v){0.f, 0.f, 0.f, 0.f};
        acc[nt] = __builtin_amdgcn_mfma_f32_16x16x32_bf16(af0, bf0[nt], acc[nt], 0, 0, 0);
        acc[nt] = __builtin_amdgcn_mfma_f32_16x16x32_bf16(af1, bf1[nt], acc[nt], 0, 0, 0);
      }
#pragma unroll
      for (int r = 0; r < 4; ++r) {
        bool v = (tbase + quad * 4 + r) < n;
#pragma unroll
        for (int nt = 0; nt < 4; ++nt) {
          float val = acc[nt][r] + b2r[nt];
          if (v) {
            s1[nt] += val; s2[nt] += val * val;
            mx[nt] = val > mx[nt] ? val : mx[nt];
            mn[nt] = val < mn[nt] ? val : mn[nt];
          }
        }
      }
    };

    int icA = __shfl(rv0, col);       icA = (col < n) ? icA : 0;
    int icB = __shfl(rv0, 16 + col);  icB = (16 + col < n) ? icB : 0;
    float4 zAa = zs4[(size_t)icA * 16 + quad * 2];
    float4 zAb = zs4[(size_t)icA * 16 + quad * 2 + 1];
    float4 zAc = zs4[(size_t)icA * 16 + 8 + quad * 2];
    float4 zAd = zs4[(size_t)icA * 16 + 8 + quad * 2 + 1];
    float4 zBa = zs4[(size_t)icB * 16 + quad * 2];
    float4 zBb = zs4[(size_t)icB * 16 + quad * 2 + 1];
    float4 zBc = zs4[(size_t)icB * 16 + 8 + quad * 2];
    float4 zBd = zs4[(size_t)icB * 16 + 8 + quad * 2 + 1];
    tile_body(0, zAa, zAb, zAc, zAd);
    if (n > 16) tile_body(16, zBa, zBb, zBc, zBd);
    for (int ti = 2; ti * 16 < n; ++ti) {
      int gi = ti * 16 + col;
      int v0 = __shfl(rv0, gi & 63);
      int v1 = __shfl(rv1, gi & 63);
      int ic = (gi < 64) ? v0 : v1;
      ic = (gi < n) ? ic : 0;
      float4 za = zs4[(size_t)ic * 16 + quad * 2];
      float4 zb = zs4[(size_t)ic * 16 + quad * 2 + 1];
      float4 zc = zs4[(size_t)ic * 16 + 8 + quad * 2];
      float4 zd = zs4[(size_t)ic * 16 + 8 + quad * 2 + 1];
      tile_body(ti * 16, za, zb, zc, zd);
    }
#pragma unroll
    for (int nt = 0; nt < 4; ++nt) {
      mx[nt] = fmaxf(mx[nt], __shfl_xor(mx[nt], 16));
      mx[nt] = fmaxf(mx[nt], __shfl_xor(mx[nt], 32));
      mn[nt] = fminf(mn[nt], __shfl_xor(mn[nt], 16));
      mn[nt] = fminf(mn[nt], __shfl_xor(mn[nt], 32));
    }
    if (quad == 0) {
#pragma unroll
      for (int nt = 0; nt < 4; ++nt) {
        mmax[(size_t)row * 64 + nt * 16 + col] = mx[nt];
        mmin[(size_t)row * 64 + nt * 16 + col] = mn[nt];
      }
    }
    rv0 = nrv0; rv1 = nrv1;
    ya = nya; yb = nyb; yc = nyc; yd = nyd;
  }
  // block-level stats reduction -> partial buffer (32-way de-contended)
  if (t < 128) ss[t >> 6][t & 63] = 0.f;
  __syncthreads();
#pragma unroll
  for (int nt = 0; nt < 4; ++nt) {
    s1[nt] += __shfl_xor(s1[nt], 16);
    s1[nt] += __shfl_xor(s1[nt], 32);
    s2[nt] += __shfl_xor(s2[nt], 16);
    s2[nt] += __shfl_xor(s2[nt], 32);
  }
  if (quad == 0) {
#pragma unroll
    for (int nt = 0; nt < 4; ++nt) {
      atomicAdd(&ss[0][nt * 16 + col], s1[nt]);
      atomicAdd(&ss[1][nt * 16 + col], s2[nt]);
    }
  }
  __syncthreads();
  const int pb = (blockIdx.x & (NPART - 1)) * 128;
  if (t < 64)       atomicAdd(&bn2p[pb + t], ss[0][t]);
  else if (t < 128) atomicAdd(&bn2p[pb + 64 + (t - 64)], ss[1][t - 64]);
}

// ---------------- finalize: BN2 affine of per-row max/min + relu + empties -
__global__ __launch_bounds__(256) void finalize_out(
    const float* __restrict__ bn2p, const float* __restrict__ g2,
    const float* __restrict__ beta2, const int* __restrict__ cnt,
    const float* __restrict__ mmax, const float* __restrict__ mmin,
    const int* __restrict__ ovf_cnt, const int* __restrict__ ovf,
    const int* __restrict__ nbr, const float* __restrict__ ys,
    const float* __restrict__ zs, const float* __restrict__ W2,
    const float* __restrict__ b2, float* __restrict__ outp) {
  __shared__ float red[128];
  const int t = threadIdx.x;
  if (t < 128) {
    float v = 0.f;
#pragma unroll
    for (int k = 0; k < NPART; ++k) v += bn2p[k * 128 + t];
    red[t] = v;
  }
  __syncthreads();
  const int idx = blockIdx.x * 256 + t;
  const int row = idx >> 6, ch = idx & 63;
  constexpr float invE = 1.0f / NEDGE;
  float mu  = red[ch] * invE;
  float var = red[64 + ch] * invE - mu * mu;
  float a2  = g2[ch] * rsqrtf(var + 1e-5f);
  float c2  = beta2[ch] - mu * a2;
  float h = (a2 >= 0.f) ? mmax[idx] : mmin[idx];
  int ov = ovf_cnt[0]; ov = ov > OVCAP ? OVCAP : ov;
  for (int u = 0; u < ov; ++u) {
    int e = ovf[u];
    if (nbr[e] == row) {
      int ic = e / KNN_K;
      float accv = 0.f;
      for (int k = 0; k < 64; ++k) {
        float hh = ys[(size_t)row * 64 + k] + zs[(size_t)ic * 64 + k];
        hh = hh > 0.f ? hh : 0.f;
        accv = fmaf(hh, W2[ch * 64 + k], accv);
      }
      float v = accv + b2[ch];
      if (a2 >= 0.f) h = v > h ? v : h; else h = v < h ? v : h;
    }
  }
  float o = (cnt[row] > 0) ? fmaf(h, a2, c2) : 0.0f;
  outp[idx] = o > 0.f ? o : 0.f;
}

// --------------------------------------------------------------- launch ----
extern "C" void kernel_launch(void* const* d_in, const int* in_sizes, int n_in,
                              void* d_out, int out_size, void* d_ws, size_t ws_size,
                              hipStream_t stream) {
  (void)in_sizes; (void)n_in; (void)out_size; (void)ws_size;
  const float* x     = (const float*)d_in[0];
  const float* pos   = (const float*)d_in[1];
  const float* W1    = (const float*)d_in[3];
  const float* b1    = (const float*)d_in[4];
  const float* g1    = (const float*)d_in[5];
  const float* beta1 = (const float*)d_in[6];
  const float* W2    = (const float*)d_in[7];
  const float* b2    = (const float*)d_in[8];
  const float* g2    = (const float*)d_in[9];
  const float* beta2 = (const float*)d_in[10];
  float* outp = (float*)d_out;

  char* w = (char*)d_ws;
  int*   nbr     = (int*)w;                            // 1,310,720 B
  float* yv      = (float*)(w + 1310720);              // 4,194,304 B
  float* zv      = (float*)(w + 5505024);              // 4,194,304 B
  int*   cnt     = (int*)(w + 9700352);                // 65,536 B
  int*   ovf_cnt = (int*)(w + 9765888);                // 64 B
  int*   ovf     = (int*)(w + 9765952);                // 32,768 B
  int*   rev     = (int*)(w + 9798720);                // 8,388,608 B -> 18,187,328
  float* mmax    = (float*)(w + 18187328);             // 4,194,304 B
  float* mmin    = (float*)(w + 22381632);             // 4,194,304 B -> 26,575,936
  float* ys      = (float*)(w + 26575936);             // 4,194,304 B
  float* zs      = (float*)(w + 30770240);             // 4,194,304 B -> 34,964,544
  float* bn1p    = (float*)(w + 34964544);             // 16,384 B (32x128)
  float* bn2p    = (float*)(w + 34980928);             // 16,384 B -> 34,997,312

  hipMemsetAsync(cnt, 0, 65536 + 64, stream);
  hipMemsetAsync(bn1p, 0, 32768, stream);

  knn_kernel<<<NPT / 16, 256, 0, stream>>>(pos, nbr, cnt, ovf_cnt, ovf, rev);
  node_gemm<<<NPT / 16, 256, 0, stream>>>(x, W1, yv, zv);
  bn1_stats<<<NPT / 16, 256, 0, stream>>>(nbr, (const float4*)yv, (const float4*)zv, b1, bn1p);
  scale_yz<<<NPT * 16 / 256, 256, 0, stream>>>(
      (const float4*)yv, (const float4*)zv, bn1p, g1, beta1, b1,
      (float4*)ys, (float4*)zs);
  gemm2_row<<<NPT / 16, 256, 0, stream>>>(
      (const float4*)ys, (const float4*)zs, W2, b2,
      cnt, rev, bn2p, mmax, mmin);
  finalize_out<<<NPT * 64 / 256, 256, 0, stream>>>(
      bn2p, g2, beta2, cnt, mmax, mmin, ovf_cnt, ovf, nbr,
      ys, zs, W2, b2, outp);
}